// Round 1
// baseline (5998.650 us; speedup 1.0000x reference)
//
#include <hip/hip_runtime.h>
#include <hip/hip_bf16.h>
#include <math.h>

#define N_NODES 8192
#define N_EDGES 16384
#define N_E3    1024
#define NGRAPH  256
#define NPG     32          // nodes per graph (batch = repeat(arange(256), 32))
#define SLOPE   (11.0f/48.0f)
#define BN_EPS  1e-5f

__device__ __forceinline__ float rrelu(float v){ return v >= 0.f ? v : SLOPE*v; }
__device__ __forceinline__ float sigm(float v){ return 1.f/(1.f+__expf(-v)); }

// ---------- BN stats: one block (256 thr) per feature, biased variance ----------
__global__ void bn_stats_k(const float* __restrict__ X, int nrow, int F,
                           float* __restrict__ mean, float* __restrict__ var) {
  int f = blockIdx.x, t = threadIdx.x;
  __shared__ float s1[256], s2[256];
  float a = 0.f, b = 0.f;
  for (int n = t; n < nrow; n += 256) {
    float v = X[(size_t)n * F + f];
    a += v; b += v * v;
  }
  s1[t] = a; s2[t] = b; __syncthreads();
  for (int w = 128; w > 0; w >>= 1) {
    if (t < w) { s1[t] += s1[t+w]; s2[t] += s2[t+w]; }
    __syncthreads();
  }
  if (t == 0) {
    float m = s1[0] / (float)nrow;
    mean[f] = m;
    var[f]  = s2[0] / (float)nrow - m * m;
  }
}

// ---------- node embed: rrelu(bn(x) @ Wn + bnode)  [N,8]->[N,64] ----------
__global__ void node_embed_k(const float* __restrict__ x,
                             const float* __restrict__ mean, const float* __restrict__ var,
                             const float* __restrict__ g, const float* __restrict__ b,
                             const float* __restrict__ Wn, const float* __restrict__ bnode,
                             float* __restrict__ out) {
  int idx = blockIdx.x * blockDim.x + threadIdx.x;
  if (idx >= N_NODES * 64) return;
  int n = idx >> 6, o = idx & 63;
  float acc = bnode[o];
  #pragma unroll
  for (int i = 0; i < 8; i++) {
    float xn = (x[n*8+i] - mean[i]) * rsqrtf(var[i] + BN_EPS) * g[i] + b[i];
    acc += xn * Wn[i*64 + o];
  }
  out[idx] = rrelu(acc);
}

// ---------- edge embed: rrelu(edge_attr @ We + be)  [E,19]->[E,12] ----------
__global__ void edge_embed_k(const float* __restrict__ eattr,
                             const float* __restrict__ We, const float* __restrict__ be,
                             float* __restrict__ ea) {
  int idx = blockIdx.x * blockDim.x + threadIdx.x;
  if (idx >= N_EDGES * 12) return;
  int e = idx / 12, j = idx - e * 12;
  float acc = be[j];
  #pragma unroll
  for (int k = 0; k < 19; k++) acc += eattr[e*19+k] * We[k*12 + j];
  ea[idx] = rrelu(acc);
}

// ---------- NNConv layer 1 message: block per edge (64 thr) ----------
__global__ void conv1_k(const float* __restrict__ feat, const int* __restrict__ ei,
                        const float* __restrict__ ea, const float* __restrict__ Wnn1,
                        float* __restrict__ s, float* __restrict__ cnt) {
  int e = blockIdx.x, o = threadIdx.x;
  int src = ei[e], dst = ei[N_EDGES + e];
  __shared__ float xs[64];
  xs[o] = feat[src*64 + o];
  __syncthreads();
  float msg = 0.f;
  for (int k = 0; k < 12; k++) {
    const float* W = Wnn1 + k*4096 + o;
    float tmp = 0.f;
    #pragma unroll
    for (int i = 0; i < 64; i++) tmp += xs[i] * W[i << 6];
    msg += ea[e*12 + k] * tmp;
  }
  atomicAdd(&s[dst*64 + o], msg);
  if (o == 0) atomicAdd(&cnt[dst], 1.0f);
}

// ---------- GRU layer 1: block per node (64 thr); h updated in place ----------
__global__ void gru1_k(const float* __restrict__ s, const float* __restrict__ cnt,
                       const float* __restrict__ bias,
                       const float* __restrict__ Wih, const float* __restrict__ Whh,
                       const float* __restrict__ bih, const float* __restrict__ bhh,
                       float* __restrict__ hbuf) {
  int n = blockIdx.x, t = threadIdx.x;
  __shared__ float m[64], h[64];
  float dn = fmaxf(cnt[n], 1.0f);
  m[t] = rrelu(s[n*64+t] / dn + bias[t]);
  h[t] = hbuf[n*64+t];
  __syncthreads();
  float gi[3], gh[3];
  #pragma unroll
  for (int p = 0; p < 3; p++) {
    int j = p*64 + t;
    float a = bih[j];
    const float* W = Wih + j*64;
    for (int i = 0; i < 64; i++) a += m[i] * W[i];
    gi[p] = a;
    float bsum = bhh[j];
    const float* V = Whh + j*64;
    for (int i = 0; i < 64; i++) bsum += h[i] * V[i];
    gh[p] = bsum;
  }
  float r  = sigm(gi[0] + gh[0]);
  float z  = sigm(gi[1] + gh[1]);
  float nn = tanhf(gi[2] + r * gh[2]);
  hbuf[n*64+t] = (1.f - z) * nn + z * h[t];
}

// ---------- FC1: rrelu(bn(out) @ Wc1 + bc1) [N,64]->[N,128] ----------
__global__ void fc1_k(const float* __restrict__ A,
                      const float* __restrict__ mean, const float* __restrict__ var,
                      const float* __restrict__ g, const float* __restrict__ b,
                      const float* __restrict__ Wc1, const float* __restrict__ bc1,
                      float* __restrict__ y1) {
  int idx = blockIdx.x * blockDim.x + threadIdx.x;
  if (idx >= N_NODES * 128) return;
  int n = idx >> 7, o = idx & 127;
  float acc = bc1[o];
  for (int i = 0; i < 64; i++) {
    float xn = (A[n*64+i] - mean[i]) * rsqrtf(var[i] + BN_EPS) * g[i] + b[i];
    acc += xn * Wc1[i*128 + o];
  }
  y1[idx] = rrelu(acc);
}

// ---------- FC2: rrelu(y1 @ Wc2 + bc2) [N,128]->[N,128] ----------
__global__ void fc2_k(const float* __restrict__ y1,
                      const float* __restrict__ Wc2, const float* __restrict__ bc2,
                      float* __restrict__ B) {
  int idx = blockIdx.x * blockDim.x + threadIdx.x;
  if (idx >= N_NODES * 128) return;
  int n = idx >> 7, o = idx & 127;
  float acc = bc2[o];
  for (int i = 0; i < 128; i++) acc += y1[n*128+i] * Wc2[i*128 + o];
  B[idx] = rrelu(acc);
}

// ---------- NNConv layer 2: block per symmetrized edge (128 thr) ----------
__global__ void conv2_k(const float* __restrict__ feat, const int* __restrict__ ei3,
                        const float* __restrict__ ea3, const float* __restrict__ Wnn2,
                        float* __restrict__ s, float* __restrict__ cnt) {
  int e = blockIdx.x, o = threadIdx.x;
  int eb = (e < N_E3) ? e : e - N_E3;
  int src, dst;
  if (e < N_E3) { src = ei3[eb];        dst = ei3[N_E3 + eb]; }
  else          { src = ei3[N_E3 + eb]; dst = ei3[eb]; }
  __shared__ float xs[128];
  xs[o] = feat[src*128 + o];
  __syncthreads();
  float msg = 0.f;
  for (int k = 0; k < 8; k++) {
    const float* W = Wnn2 + k*16384 + o;
    float tmp = 0.f;
    #pragma unroll
    for (int i = 0; i < 128; i++) tmp += xs[i] * W[i << 7];
    msg += ea3[eb*8 + k] * tmp;
  }
  atomicAdd(&s[dst*128 + o], msg);
  if (o == 0) atomicAdd(&cnt[dst], 1.0f);
}

// ---------- GRU layer 2: block per node (128 thr) ----------
__global__ void gru2_k(const float* __restrict__ s, const float* __restrict__ cnt,
                       const float* __restrict__ bias,
                       const float* __restrict__ Wih, const float* __restrict__ Whh,
                       const float* __restrict__ bih, const float* __restrict__ bhh,
                       float* __restrict__ hbuf) {
  int n = blockIdx.x, t = threadIdx.x;
  __shared__ float m[128], h[128];
  float dn = fmaxf(cnt[n], 1.0f);
  m[t] = rrelu(s[n*128+t] / dn + bias[t]);
  h[t] = hbuf[n*128+t];
  __syncthreads();
  float gi[3], gh[3];
  #pragma unroll
  for (int p = 0; p < 3; p++) {
    int j = p*128 + t;
    float a = bih[j];
    const float* W = Wih + j*128;
    for (int i = 0; i < 128; i++) a += m[i] * W[i];
    gi[p] = a;
    float bsum = bhh[j];
    const float* V = Whh + j*128;
    for (int i = 0; i < 128; i++) bsum += h[i] * V[i];
    gh[p] = bsum;
  }
  float r  = sigm(gi[0] + gh[0]);
  float z  = sigm(gi[1] + gh[1]);
  float nn = tanhf(gi[2] + r * gh[2]);
  hbuf[n*128+t] = (1.f - z) * nn + z * h[t];
}

// ---------- Set2Set: one block (128 thr) per graph, 3 steps in LDS ----------
__global__ void set2set_k(const float* __restrict__ x,
                          const float* __restrict__ Ws_ih, const float* __restrict__ Ws_hh,
                          const float* __restrict__ bs_ih, const float* __restrict__ bs_hh,
                          float* __restrict__ qpool) {
  int g = blockIdx.x, t = threadIdx.x;   // 128 threads
  __shared__ float h[128], c[128], q[256], ebuf[NPG], red[1];
  h[t] = 0.f; c[t] = 0.f; q[t] = 0.f; q[128+t] = 0.f;
  __syncthreads();
  for (int step = 0; step < 3; step++) {
    // LSTM gates: j = t (i), 128+t (f), 256+t (g), 384+t (o)
    float gv[4];
    #pragma unroll
    for (int gg = 0; gg < 4; gg++) {
      int j = gg*128 + t;
      float acc = bs_ih[j] + bs_hh[j];
      const float* Wi = Ws_ih + (size_t)j*256;
      for (int i = 0; i < 256; i++) acc += q[i] * Wi[i];
      const float* Wh = Ws_hh + (size_t)j*128;
      for (int i = 0; i < 128; i++) acc += h[i] * Wh[i];
      gv[gg] = acc;
    }
    __syncthreads();
    float ci = sigm(gv[1]) * c[t] + sigm(gv[0]) * tanhf(gv[2]);
    float hi = sigm(gv[3]) * tanhf(ci);
    c[t] = ci; h[t] = hi;
    __syncthreads();
    // attention scores for this graph's 32 nodes
    if (t < NPG) {
      int node = g*NPG + t;
      float acc = 0.f;
      for (int i = 0; i < 128; i++) acc += x[(size_t)node*128 + i] * h[i];
      ebuf[t] = acc;
    }
    __syncthreads();
    if (t == 0) {
      float mx = ebuf[0];
      for (int i = 1; i < NPG; i++) mx = fmaxf(mx, ebuf[i]);
      float den = 0.f;
      for (int i = 0; i < NPG; i++) { ebuf[i] = __expf(ebuf[i] - mx); den += ebuf[i]; }
      red[0] = den;
    }
    __syncthreads();
    float den = red[0];
    float racc = 0.f;
    for (int nn = 0; nn < NPG; nn++)
      racc += (ebuf[nn] / den) * x[(size_t)(g*NPG + nn)*128 + t];
    __syncthreads();
    q[t] = h[t]; q[128+t] = racc;
    __syncthreads();
  }
  qpool[g*256 + t]       = q[t];
  qpool[g*256 + 128 + t] = q[128+t];
}

// ---------- build yhat [E3, 640] ----------
__global__ void yhat_k(const float* __restrict__ feat, const int* __restrict__ ei3,
                       const int* __restrict__ batch, const float* __restrict__ qpool,
                       float* __restrict__ yhat) {
  int idx = blockIdx.x * blockDim.x + threadIdx.x;
  if (idx >= N_E3 * 640) return;
  int e = idx / 640, j = idx - e * 640;
  int s0 = ei3[e], s1 = ei3[N_E3 + e];
  float v;
  if (j < 128)      { v = 0.5f * (feat[s0*128+j] + feat[s1*128+j]); }
  else if (j < 256) { int jj = j-128; v = feat[s0*128+jj] * feat[s1*128+jj]; }
  else if (j < 384) { int jj = j-256; float d = feat[s0*128+jj] - feat[s1*128+jj]; v = d*d; }
  else              { int cbi = batch[s0]; v = qpool[cbi*256 + (j-384)]; }
  yhat[idx] = v;
}

// ---------- final: out[e] = sum_j bn(yhat)[e,j] * (ea3@Ww)[e,j] + (ea3@Wb)[e] ----------
__global__ void final_k(const float* __restrict__ yhat,
                        const float* __restrict__ mean, const float* __restrict__ var,
                        const float* __restrict__ g, const float* __restrict__ b,
                        const float* __restrict__ ea3,
                        const float* __restrict__ Ww, const float* __restrict__ Wb,
                        float* __restrict__ out) {
  int e = blockIdx.x, t = threadIdx.x;  // 128 threads
  __shared__ float red[128];
  float av[8];
  #pragma unroll
  for (int k = 0; k < 8; k++) av[k] = ea3[e*8 + k];
  float acc = 0.f;
  for (int j = t; j < 640; j += 128) {
    float yn = (yhat[(size_t)e*640 + j] - mean[j]) * rsqrtf(var[j] + BN_EPS) * g[j] + b[j];
    float wj = 0.f;
    #pragma unroll
    for (int k = 0; k < 8; k++) wj += av[k] * Ww[k*640 + j];
    acc += yn * wj;
  }
  red[t] = acc; __syncthreads();
  for (int w = 64; w > 0; w >>= 1) {
    if (t < w) red[t] += red[t+w];
    __syncthreads();
  }
  if (t == 0) {
    float bb = 0.f;
    #pragma unroll
    for (int k = 0; k < 8; k++) bb += av[k] * Wb[k];
    out[e] = red[0] + bb;
  }
}

extern "C" void kernel_launch(void* const* d_in, const int* in_sizes, int n_in,
                              void* d_out, int out_size, void* d_ws, size_t ws_size,
                              hipStream_t stream) {
  const float* x      = (const float*)d_in[0];
  const int*   ei     = (const int*)  d_in[1];
  const float* eattr  = (const float*)d_in[2];
  const int*   ei3    = (const int*)  d_in[3];
  const float* ea3    = (const float*)d_in[4];
  const int*   batch  = (const int*)  d_in[5];
  const float* bnx_g  = (const float*)d_in[6];
  const float* bnx_b  = (const float*)d_in[7];
  const float* Wn     = (const float*)d_in[8];
  const float* bnode  = (const float*)d_in[9];
  const float* We     = (const float*)d_in[10];
  const float* be     = (const float*)d_in[11];
  const float* Wnn1   = (const float*)d_in[12];
  const float* bias1  = (const float*)d_in[13];
  const float* Wih1   = (const float*)d_in[14];
  const float* Whh1   = (const float*)d_in[15];
  const float* bih1   = (const float*)d_in[16];
  const float* bhh1   = (const float*)d_in[17];
  const float* bnc_g  = (const float*)d_in[18];
  const float* bnc_b  = (const float*)d_in[19];
  const float* Wc1    = (const float*)d_in[20];
  const float* bc1    = (const float*)d_in[21];
  const float* Wc2    = (const float*)d_in[22];
  const float* bc2    = (const float*)d_in[23];
  const float* Wnn2   = (const float*)d_in[24];
  const float* bias2  = (const float*)d_in[25];
  const float* Wih2   = (const float*)d_in[26];
  const float* Whh2   = (const float*)d_in[27];
  const float* bih2   = (const float*)d_in[28];
  const float* bhh2   = (const float*)d_in[29];
  const float* Ws_ih  = (const float*)d_in[30];
  const float* Ws_hh  = (const float*)d_in[31];
  const float* bs_ih  = (const float*)d_in[32];
  const float* bs_hh  = (const float*)d_in[33];
  const float* bno_g  = (const float*)d_in[34];
  const float* bno_b  = (const float*)d_in[35];
  const float* Ww     = (const float*)d_in[36];
  const float* Wb     = (const float*)d_in[37];
  float* out = (float*)d_out;

  // workspace carve-up (floats)
  float* W = (float*)d_ws;
  size_t off = 0;
  float* ea12  = W + off; off += (size_t)N_EDGES * 12;   // edge embeddings
  float* nodeA = W + off; off += (size_t)N_NODES * 64;   // layer-1 node state
  float* sbuf  = W + off; off += (size_t)N_NODES * 128;  // scatter sum
  float* cnt   = W + off; off += (size_t)N_NODES;        // scatter count
  float* y1    = W + off; off += (size_t)N_NODES * 128;  // fc1 out
  float* nodeB = W + off; off += (size_t)N_NODES * 128;  // layer-2 node state
  float* qpool = W + off; off += (size_t)NGRAPH * 256;   // set2set output
  float* yhat  = W + off; off += (size_t)N_E3 * 640;
  float* mean  = W + off; off += 640;
  float* var   = W + off; off += 640;
  (void)off; (void)ws_size; (void)in_sizes; (void)n_in; (void)out_size;

  // 1. node embed
  bn_stats_k<<<8, 256, 0, stream>>>(x, N_NODES, 8, mean, var);
  node_embed_k<<<(N_NODES*64 + 255)/256, 256, 0, stream>>>(x, mean, var, bnx_g, bnx_b, Wn, bnode, nodeA);
  // 2. edge embed
  edge_embed_k<<<(N_EDGES*12 + 255)/256, 256, 0, stream>>>(eattr, We, be, ea12);

  // 3. layer-1 conv+GRU x2 (out == h, updated in place)
  for (int it = 0; it < 2; it++) {
    hipMemsetAsync(sbuf, 0, (size_t)N_NODES*64*sizeof(float), stream);
    hipMemsetAsync(cnt,  0, (size_t)N_NODES*sizeof(float), stream);
    conv1_k<<<N_EDGES, 64, 0, stream>>>(nodeA, ei, ea12, Wnn1, sbuf, cnt);
    gru1_k<<<N_NODES, 64, 0, stream>>>(sbuf, cnt, bias1, Wih1, Whh1, bih1, bhh1, nodeA);
  }

  // 4. BN + FC1 + FC2
  bn_stats_k<<<64, 256, 0, stream>>>(nodeA, N_NODES, 64, mean, var);
  fc1_k<<<(N_NODES*128 + 255)/256, 256, 0, stream>>>(nodeA, mean, var, bnc_g, bnc_b, Wc1, bc1, y1);
  fc2_k<<<(N_NODES*128 + 255)/256, 256, 0, stream>>>(y1, Wc2, bc2, nodeB);

  // 5. layer-2 conv+GRU x2 on symmetrized E3 edges
  for (int it = 0; it < 2; it++) {
    hipMemsetAsync(sbuf, 0, (size_t)N_NODES*128*sizeof(float), stream);
    hipMemsetAsync(cnt,  0, (size_t)N_NODES*sizeof(float), stream);
    conv2_k<<<2*N_E3, 128, 0, stream>>>(nodeB, ei3, ea3, Wnn2, sbuf, cnt);
    gru2_k<<<N_NODES, 128, 0, stream>>>(sbuf, cnt, bias2, Wih2, Whh2, bih2, bhh2, nodeB);
  }

  // 6. set2set pooling
  set2set_k<<<NGRAPH, 128, 0, stream>>>(nodeB, Ws_ih, Ws_hh, bs_ih, bs_hh, qpool);

  // 7. yhat features + BN + weighted sum
  yhat_k<<<(N_E3*640 + 255)/256, 256, 0, stream>>>(nodeB, ei3, batch, qpool, yhat);
  bn_stats_k<<<640, 256, 0, stream>>>(yhat, N_E3, 640, mean, var);
  final_k<<<N_E3, 128, 0, stream>>>(yhat, mean, var, bno_g, bno_b, ea3, Ww, Wb, out);
}

// Round 2
// 408.366 us; speedup vs baseline: 14.6894x; 14.6894x over previous
//
#include <hip/hip_runtime.h>
#include <hip/hip_bf16.h>
#include <math.h>

#define N_NODES 8192
#define N_EDGES 16384
#define N_E3    1024
#define NGRAPH  256
#define NPG     32
#define SLOPE   (11.0f/48.0f)
#define BN_EPS  1e-5f

__device__ __forceinline__ float rrelu(float v){ return v >= 0.f ? v : SLOPE*v; }
__device__ __forceinline__ float sigm(float v){ return 1.f/(1.f+__expf(-v)); }

// ================= generic tiled GEMM: C[M,J] = act(A[M,K] @ W'[J,K]^T + bias) ==========
// WT=true: W stored [J,K] row-major (row per output).  WT=false: W stored [K,J].
// BM=BJ=64, BK=32, 256 threads, 4x4 accum per thread. LDS tiles transposed: [kk][n].
#define BK 32
template<bool WT, int ACT>
__global__ __launch_bounds__(256) void gemm_k(const float* __restrict__ A,
                                              const float* __restrict__ W,
                                              const float* __restrict__ bias,
                                              float* __restrict__ C,
                                              int M, int K, int J) {
  __shared__ float As[BK][68];
  __shared__ float Ws[BK][68];
  int t = threadIdx.x;
  int jt = J >> 6;
  int bm = blockIdx.x / jt, bj = blockIdx.x % jt;
  int n0 = bm << 6, j0 = bj << 6;
  int tx = t & 15, ty = t >> 4;
  int lr = t >> 2, lq = t & 3;          // transpose-loader: row 0..63, float4 col 0..3
  float acc[4][4] = {};

  for (int k0 = 0; k0 < K; k0 += BK) {
    { // A tile -> As[kk][n]
      const float* src = A + (size_t)(n0 + lr) * K + k0;
      float4 v0 = *(const float4*)(src + lq*4);
      float4 v1 = *(const float4*)(src + lq*4 + 16);
      As[lq*4+0][lr]=v0.x; As[lq*4+1][lr]=v0.y; As[lq*4+2][lr]=v0.z; As[lq*4+3][lr]=v0.w;
      As[lq*4+16][lr]=v1.x; As[lq*4+17][lr]=v1.y; As[lq*4+18][lr]=v1.z; As[lq*4+19][lr]=v1.w;
    }
    if (WT) { // W[J,K] tile -> Ws[kk][jj]
      const float* src = W + (size_t)(j0 + lr) * K + k0;
      float4 v0 = *(const float4*)(src + lq*4);
      float4 v1 = *(const float4*)(src + lq*4 + 16);
      Ws[lq*4+0][lr]=v0.x; Ws[lq*4+1][lr]=v0.y; Ws[lq*4+2][lr]=v0.z; Ws[lq*4+3][lr]=v0.w;
      Ws[lq*4+16][lr]=v1.x; Ws[lq*4+17][lr]=v1.y; Ws[lq*4+18][lr]=v1.z; Ws[lq*4+19][lr]=v1.w;
    } else {  // W[K,J] tile: already [kk][jj]
      int wr = t >> 3, wq = t & 7;
      const float* src = W + (size_t)(k0 + wr) * J + j0;
      *(float4*)&Ws[wr][wq*4]      = *(const float4*)(src + wq*4);
      *(float4*)&Ws[wr][wq*4 + 32] = *(const float4*)(src + wq*4 + 32);
    }
    __syncthreads();
    #pragma unroll
    for (int kk = 0; kk < BK; kk++) {
      float4 a = *(const float4*)&As[kk][ty*4];
      float4 w = *(const float4*)&Ws[kk][tx*4];
      acc[0][0]+=a.x*w.x; acc[0][1]+=a.x*w.y; acc[0][2]+=a.x*w.z; acc[0][3]+=a.x*w.w;
      acc[1][0]+=a.y*w.x; acc[1][1]+=a.y*w.y; acc[1][2]+=a.y*w.z; acc[1][3]+=a.y*w.w;
      acc[2][0]+=a.z*w.x; acc[2][1]+=a.z*w.y; acc[2][2]+=a.z*w.z; acc[2][3]+=a.z*w.w;
      acc[3][0]+=a.w*w.x; acc[3][1]+=a.w*w.y; acc[3][2]+=a.w*w.z; acc[3][3]+=a.w*w.w;
    }
    __syncthreads();
  }
  int j = j0 + tx*4;
  float4 bv = bias ? *(const float4*)&bias[j] : make_float4(0.f,0.f,0.f,0.f);
  #pragma unroll
  for (int r = 0; r < 4; r++) {
    float4 o;
    o.x = acc[r][0] + bv.x; o.y = acc[r][1] + bv.y;
    o.z = acc[r][2] + bv.z; o.w = acc[r][3] + bv.w;
    if (ACT == 1) { o.x = rrelu(o.x); o.y = rrelu(o.y); o.z = rrelu(o.z); o.w = rrelu(o.w); }
    *(float4*)&C[(size_t)(n0 + ty*4 + r) * J + j] = o;
  }
}

// ================= small kernels =================
__global__ void bn_stats_k(const float* __restrict__ X, int nrow, int F,
                           float* __restrict__ mean, float* __restrict__ var) {
  int f = blockIdx.x, t = threadIdx.x;
  __shared__ float s1[256], s2[256];
  float a = 0.f, b = 0.f;
  for (int n = t; n < nrow; n += 256) {
    float v = X[(size_t)n * F + f];
    a += v; b += v * v;
  }
  s1[t] = a; s2[t] = b; __syncthreads();
  for (int w = 128; w > 0; w >>= 1) {
    if (t < w) { s1[t] += s1[t+w]; s2[t] += s2[t+w]; }
    __syncthreads();
  }
  if (t == 0) {
    float m = s1[0] / (float)nrow;
    mean[f] = m;
    var[f]  = s2[0] / (float)nrow - m * m;
  }
}

__global__ void node_embed_k(const float* __restrict__ x,
                             const float* __restrict__ mean, const float* __restrict__ var,
                             const float* __restrict__ g, const float* __restrict__ b,
                             const float* __restrict__ Wn, const float* __restrict__ bnode,
                             float* __restrict__ out) {
  int idx = blockIdx.x * blockDim.x + threadIdx.x;
  if (idx >= N_NODES * 64) return;
  int n = idx >> 6, o = idx & 63;
  float acc = bnode[o];
  #pragma unroll
  for (int i = 0; i < 8; i++) {
    float xn = (x[n*8+i] - mean[i]) * rsqrtf(var[i] + BN_EPS) * g[i] + b[i];
    acc += xn * Wn[i*64 + o];
  }
  out[idx] = rrelu(acc);
}

__global__ void edge_embed_k(const float* __restrict__ eattr,
                             const float* __restrict__ We, const float* __restrict__ be,
                             float* __restrict__ ea) {
  int idx = blockIdx.x * blockDim.x + threadIdx.x;
  if (idx >= N_EDGES * 12) return;
  int e = idx / 12, j = idx - e * 12;
  float acc = be[j];
  #pragma unroll
  for (int k = 0; k < 19; k++) acc += eattr[e*19+k] * We[k*12 + j];
  ea[idx] = rrelu(acc);
}

// pack: Wz1[(k*64+o)*64+i] = Wnn1[k*4096+i*64+o]; WsiT[i*512+j]=Ws_ih[j*256+i]; WshT[i*512+j]=Ws_hh[j*128+i]
__global__ void pack_k(const float* __restrict__ Wnn1, const float* __restrict__ Ws_ih,
                       const float* __restrict__ Ws_hh,
                       float* __restrict__ Wz1, float* __restrict__ WsiT, float* __restrict__ WshT) {
  int idx = blockIdx.x * 256 + threadIdx.x;
  if (idx < 49152) {
    int jj = idx >> 6, i = idx & 63;
    int k = jj >> 6, o = jj & 63;
    Wz1[idx] = Wnn1[k*4096 + i*64 + o];
  }
  if (idx < 131072) {
    int i = idx >> 9, j = idx & 511;
    WsiT[idx] = Ws_ih[j*256 + i];
  }
  if (idx < 65536) {
    int i = idx >> 9, j = idx & 511;
    WshT[idx] = Ws_hh[j*128 + i];
  }
}

// conv1 message using Z = x @ Wnn1': msg[e,o] = sum_k ea[e,k] * Z[src, k*64+o]
__global__ void conv1_msg_k(const float* __restrict__ Z, const int* __restrict__ ei,
                            const float* __restrict__ ea,
                            float* __restrict__ sbuf, float* __restrict__ cnt) {
  int idx = blockIdx.x * 256 + threadIdx.x;
  if (idx >= N_EDGES * 64) return;
  int e = idx >> 6, o = idx & 63;
  int src = ei[e], dst = ei[N_EDGES + e];
  const float* z = Z + (size_t)src * 768 + o;
  float msg = 0.f;
  #pragma unroll
  for (int k = 0; k < 12; k++) msg += ea[e*12 + k] * z[k*64];
  atomicAdd(&sbuf[dst*64 + o], msg);
  if (o == 0) atomicAdd(&cnt[dst], 1.0f);
}

// conv2: direct per-edge (weights L2-resident, coalesced across o)
__global__ void conv2_k(const float* __restrict__ feat, const int* __restrict__ ei3,
                        const float* __restrict__ ea3, const float* __restrict__ Wnn2,
                        float* __restrict__ s, float* __restrict__ cnt) {
  int e = blockIdx.x, o = threadIdx.x;
  int eb = (e < N_E3) ? e : e - N_E3;
  int src, dst;
  if (e < N_E3) { src = ei3[eb];        dst = ei3[N_E3 + eb]; }
  else          { src = ei3[N_E3 + eb]; dst = ei3[eb]; }
  __shared__ float xs[128];
  xs[o] = feat[src*128 + o];
  __syncthreads();
  float msg = 0.f;
  for (int k = 0; k < 8; k++) {
    const float* W = Wnn2 + k*16384 + o;
    float tmp = 0.f;
    #pragma unroll 32
    for (int i = 0; i < 128; i++) tmp += xs[i] * W[i << 7];
    msg += ea3[eb*8 + k] * tmp;
  }
  atomicAdd(&s[dst*128 + o], msg);
  if (o == 0) atomicAdd(&cnt[dst], 1.0f);
}

// m = rrelu(s/max(cnt,1) + bias)
template<int LOGH>
__global__ void m_prep_k(const float* __restrict__ s, const float* __restrict__ cnt,
                         const float* __restrict__ bias, float* __restrict__ m) {
  int idx = blockIdx.x * 256 + threadIdx.x;
  const int H = 1 << LOGH;
  if (idx >= N_NODES * H) return;
  int n = idx >> LOGH, f = idx & (H - 1);
  float dn = fmaxf(cnt[n], 1.0f);
  m[idx] = rrelu(s[idx] / dn + bias[f]);
}

// GRU combine: h = (1-z)*nn + z*h
template<int LOGH>
__global__ void gru_combine_k(const float* __restrict__ gi, const float* __restrict__ gh,
                              float* __restrict__ h) {
  int idx = blockIdx.x * 256 + threadIdx.x;
  const int H = 1 << LOGH;
  if (idx >= N_NODES * H) return;
  int n = idx >> LOGH, f = idx & (H - 1);
  const float* gin = gi + (size_t)n * 3 * H;
  const float* ghn = gh + (size_t)n * 3 * H;
  float r  = sigm(gin[f]       + ghn[f]);
  float z  = sigm(gin[H + f]   + ghn[H + f]);
  float nn = tanhf(gin[2*H + f] + r * ghn[2*H + f]);
  h[idx] = (1.f - z) * nn + z * h[idx];
}

// apply BN (F=64) -> Y
__global__ void bn_apply_k(const float* __restrict__ X,
                           const float* __restrict__ mean, const float* __restrict__ var,
                           const float* __restrict__ g, const float* __restrict__ b,
                           float* __restrict__ Y) {
  int idx = blockIdx.x * 256 + threadIdx.x;
  if (idx >= N_NODES * 64) return;
  int f = idx & 63;
  Y[idx] = (X[idx] - mean[f]) * rsqrtf(var[f] + BN_EPS) * g[f] + b[f];
}

// ---------- Set2Set with transpose-packed weights (coalesced gate reads) ----------
__global__ void set2set_k(const float* __restrict__ x,
                          const float* __restrict__ WsiT, const float* __restrict__ WshT,
                          const float* __restrict__ bs_ih, const float* __restrict__ bs_hh,
                          float* __restrict__ qpool) {
  int g = blockIdx.x, t = threadIdx.x;   // 128 threads
  __shared__ float h[128], c[128], q[256], ebuf[NPG], red[1];
  h[t] = 0.f; c[t] = 0.f; q[t] = 0.f; q[128+t] = 0.f;
  __syncthreads();
  for (int step = 0; step < 3; step++) {
    float gv[4];
    #pragma unroll
    for (int gg = 0; gg < 4; gg++) gv[gg] = bs_ih[gg*128 + t] + bs_hh[gg*128 + t];
    #pragma unroll 4
    for (int i = 0; i < 256; i++) {
      float qi = q[i];
      const float* w = WsiT + (size_t)i*512 + t;
      #pragma unroll
      for (int gg = 0; gg < 4; gg++) gv[gg] += qi * w[gg*128];
    }
    #pragma unroll 4
    for (int i = 0; i < 128; i++) {
      float hi = h[i];
      const float* w = WshT + (size_t)i*512 + t;
      #pragma unroll
      for (int gg = 0; gg < 4; gg++) gv[gg] += hi * w[gg*128];
    }
    __syncthreads();
    float ci = sigm(gv[1]) * c[t] + sigm(gv[0]) * tanhf(gv[2]);
    float hi = sigm(gv[3]) * tanhf(ci);
    c[t] = ci; h[t] = hi;
    __syncthreads();
    if (t < NPG) {
      int node = g*NPG + t;
      float acc = 0.f;
      for (int i = 0; i < 128; i++) acc += x[(size_t)node*128 + i] * h[i];
      ebuf[t] = acc;
    }
    __syncthreads();
    if (t == 0) {
      float mx = ebuf[0];
      for (int i = 1; i < NPG; i++) mx = fmaxf(mx, ebuf[i]);
      float den = 0.f;
      for (int i = 0; i < NPG; i++) { ebuf[i] = __expf(ebuf[i] - mx); den += ebuf[i]; }
      red[0] = den;
    }
    __syncthreads();
    float den = red[0];
    float racc = 0.f;
    for (int nn = 0; nn < NPG; nn++)
      racc += (ebuf[nn] / den) * x[(size_t)(g*NPG + nn)*128 + t];
    __syncthreads();
    q[t] = h[t]; q[128+t] = racc;
    __syncthreads();
  }
  qpool[g*256 + t]       = q[t];
  qpool[g*256 + 128 + t] = q[128+t];
}

__global__ void yhat_k(const float* __restrict__ feat, const int* __restrict__ ei3,
                       const int* __restrict__ batch, const float* __restrict__ qpool,
                       float* __restrict__ yhat) {
  int idx = blockIdx.x * blockDim.x + threadIdx.x;
  if (idx >= N_E3 * 640) return;
  int e = idx / 640, j = idx - e * 640;
  int s0 = ei3[e], s1 = ei3[N_E3 + e];
  float v;
  if (j < 128)      { v = 0.5f * (feat[s0*128+j] + feat[s1*128+j]); }
  else if (j < 256) { int jj = j-128; v = feat[s0*128+jj] * feat[s1*128+jj]; }
  else if (j < 384) { int jj = j-256; float d = feat[s0*128+jj] - feat[s1*128+jj]; v = d*d; }
  else              { int cbi = batch[s0]; v = qpool[cbi*256 + (j-384)]; }
  yhat[idx] = v;
}

__global__ void final_k(const float* __restrict__ yhat,
                        const float* __restrict__ mean, const float* __restrict__ var,
                        const float* __restrict__ g, const float* __restrict__ b,
                        const float* __restrict__ ea3,
                        const float* __restrict__ Ww, const float* __restrict__ Wb,
                        float* __restrict__ out) {
  int e = blockIdx.x, t = threadIdx.x;  // 128 threads
  __shared__ float red[128];
  float av[8];
  #pragma unroll
  for (int k = 0; k < 8; k++) av[k] = ea3[e*8 + k];
  float acc = 0.f;
  for (int j = t; j < 640; j += 128) {
    float yn = (yhat[(size_t)e*640 + j] - mean[j]) * rsqrtf(var[j] + BN_EPS) * g[j] + b[j];
    float wj = 0.f;
    #pragma unroll
    for (int k = 0; k < 8; k++) wj += av[k] * Ww[k*640 + j];
    acc += yn * wj;
  }
  red[t] = acc; __syncthreads();
  for (int w = 64; w > 0; w >>= 1) {
    if (t < w) red[t] += red[t+w];
    __syncthreads();
  }
  if (t == 0) {
    float bb = 0.f;
    #pragma unroll
    for (int k = 0; k < 8; k++) bb += av[k] * Wb[k];
    out[e] = red[0] + bb;
  }
}

extern "C" void kernel_launch(void* const* d_in, const int* in_sizes, int n_in,
                              void* d_out, int out_size, void* d_ws, size_t ws_size,
                              hipStream_t stream) {
  const float* x      = (const float*)d_in[0];
  const int*   ei     = (const int*)  d_in[1];
  const float* eattr  = (const float*)d_in[2];
  const int*   ei3    = (const int*)  d_in[3];
  const float* ea3    = (const float*)d_in[4];
  const int*   batch  = (const int*)  d_in[5];
  const float* bnx_g  = (const float*)d_in[6];
  const float* bnx_b  = (const float*)d_in[7];
  const float* Wn     = (const float*)d_in[8];
  const float* bnode  = (const float*)d_in[9];
  const float* We     = (const float*)d_in[10];
  const float* be     = (const float*)d_in[11];
  const float* Wnn1   = (const float*)d_in[12];
  const float* bias1  = (const float*)d_in[13];
  const float* Wih1   = (const float*)d_in[14];
  const float* Whh1   = (const float*)d_in[15];
  const float* bih1   = (const float*)d_in[16];
  const float* bhh1   = (const float*)d_in[17];
  const float* bnc_g  = (const float*)d_in[18];
  const float* bnc_b  = (const float*)d_in[19];
  const float* Wc1    = (const float*)d_in[20];
  const float* bc1    = (const float*)d_in[21];
  const float* Wc2    = (const float*)d_in[22];
  const float* bc2    = (const float*)d_in[23];
  const float* Wnn2   = (const float*)d_in[24];
  const float* bias2  = (const float*)d_in[25];
  const float* Wih2   = (const float*)d_in[26];
  const float* Whh2   = (const float*)d_in[27];
  const float* bih2   = (const float*)d_in[28];
  const float* bhh2   = (const float*)d_in[29];
  const float* Ws_ih  = (const float*)d_in[30];
  const float* Ws_hh  = (const float*)d_in[31];
  const float* bs_ih  = (const float*)d_in[32];
  const float* bs_hh  = (const float*)d_in[33];
  const float* bno_g  = (const float*)d_in[34];
  const float* bno_b  = (const float*)d_in[35];
  const float* Ww     = (const float*)d_in[36];
  const float* Wb     = (const float*)d_in[37];
  float* out = (float*)d_out;

  // workspace carve-up (floats)
  float* W = (float*)d_ws;
  size_t off = 0;
  float* Wz1   = W + off; off += 49152;                  // packed Wnn1' [768][64]
  float* WsiT  = W + off; off += 131072;                 // Ws_ih^T [256][512]
  float* WshT  = W + off; off += 65536;                  // Ws_hh^T [128][512]
  float* ea12  = W + off; off += (size_t)N_EDGES * 12;
  float* nodeA = W + off; off += (size_t)N_NODES * 64;
  float* xn    = W + off; off += (size_t)N_NODES * 64;
  float* sbuf  = W + off; off += (size_t)N_NODES * 128;
  float* cnt   = W + off; off += (size_t)N_NODES;
  float* mbuf  = W + off; off += (size_t)N_NODES * 128;
  float* y1    = W + off; off += (size_t)N_NODES * 128;
  float* nodeB = W + off; off += (size_t)N_NODES * 128;
  float* Z     = W + off; off += (size_t)N_NODES * 768;  // also aliased as gates
  float* qpool = W + off; off += (size_t)NGRAPH * 256;
  float* yhat  = W + off; off += (size_t)N_E3 * 640;
  float* mean  = W + off; off += 640;
  float* var   = W + off; off += 640;
  (void)off; (void)ws_size; (void)in_sizes; (void)n_in; (void)out_size;

  // gates alias Z (Z is dead once conv1_msg consumed it; layer2 never uses Z)
  float* gatesI1 = Z;                         // [8192,192]
  float* gatesH1 = Z + (size_t)N_NODES * 192;
  float* gatesI2 = Z;                         // [8192,384]
  float* gatesH2 = Z + (size_t)N_NODES * 384;

  pack_k<<<512, 256, 0, stream>>>(Wnn1, Ws_ih, Ws_hh, Wz1, WsiT, WshT);

  // 1. node embed + edge embed
  bn_stats_k<<<8, 256, 0, stream>>>(x, N_NODES, 8, mean, var);
  node_embed_k<<<(N_NODES*64 + 255)/256, 256, 0, stream>>>(x, mean, var, bnx_g, bnx_b, Wn, bnode, nodeA);
  edge_embed_k<<<(N_EDGES*12 + 255)/256, 256, 0, stream>>>(eattr, We, be, ea12);

  // 2. layer-1: (Z GEMM -> edge scatter -> m -> gate GEMMs -> combine) x2
  for (int it = 0; it < 2; it++) {
    gemm_k<true,0><<<(N_NODES/64)*(768/64), 256, 0, stream>>>(nodeA, Wz1, nullptr, Z, N_NODES, 64, 768);
    hipMemsetAsync(sbuf, 0, (size_t)N_NODES*64*sizeof(float), stream);
    hipMemsetAsync(cnt,  0, (size_t)N_NODES*sizeof(float), stream);
    conv1_msg_k<<<(N_EDGES*64)/256, 256, 0, stream>>>(Z, ei, ea12, sbuf, cnt);
    m_prep_k<6><<<(N_NODES*64)/256, 256, 0, stream>>>(sbuf, cnt, bias1, mbuf);
    gemm_k<true,0><<<(N_NODES/64)*(192/64), 256, 0, stream>>>(mbuf,  Wih1, bih1, gatesI1, N_NODES, 64, 192);
    gemm_k<true,0><<<(N_NODES/64)*(192/64), 256, 0, stream>>>(nodeA, Whh1, bhh1, gatesH1, N_NODES, 64, 192);
    gru_combine_k<6><<<(N_NODES*64)/256, 256, 0, stream>>>(gatesI1, gatesH1, nodeA);
  }

  // 3. BN + FC1 + FC2
  bn_stats_k<<<64, 256, 0, stream>>>(nodeA, N_NODES, 64, mean, var);
  bn_apply_k<<<(N_NODES*64)/256, 256, 0, stream>>>(nodeA, mean, var, bnc_g, bnc_b, xn);
  gemm_k<false,1><<<(N_NODES/64)*(128/64), 256, 0, stream>>>(xn, Wc1, bc1, y1,    N_NODES, 64, 128);
  gemm_k<false,1><<<(N_NODES/64)*(128/64), 256, 0, stream>>>(y1, Wc2, bc2, nodeB, N_NODES, 128, 128);

  // 4. layer-2: (conv2 direct -> m -> gate GEMMs -> combine) x2
  for (int it = 0; it < 2; it++) {
    hipMemsetAsync(sbuf, 0, (size_t)N_NODES*128*sizeof(float), stream);
    hipMemsetAsync(cnt,  0, (size_t)N_NODES*sizeof(float), stream);
    conv2_k<<<2*N_E3, 128, 0, stream>>>(nodeB, ei3, ea3, Wnn2, sbuf, cnt);
    m_prep_k<7><<<(N_NODES*128)/256, 256, 0, stream>>>(sbuf, cnt, bias2, mbuf);
    gemm_k<true,0><<<(N_NODES/64)*(384/64), 256, 0, stream>>>(mbuf,  Wih2, bih2, gatesI2, N_NODES, 128, 384);
    gemm_k<true,0><<<(N_NODES/64)*(384/64), 256, 0, stream>>>(nodeB, Whh2, bhh2, gatesH2, N_NODES, 128, 384);
    gru_combine_k<7><<<(N_NODES*128)/256, 256, 0, stream>>>(gatesI2, gatesH2, nodeB);
  }

  // 5. set2set
  set2set_k<<<NGRAPH, 128, 0, stream>>>(nodeB, WsiT, WshT, bs_ih, bs_hh, qpool);

  // 6. yhat + BN + weighted sum
  yhat_k<<<(N_E3*640 + 255)/256, 256, 0, stream>>>(nodeB, ei3, batch, qpool, yhat);
  bn_stats_k<<<640, 256, 0, stream>>>(yhat, N_E3, 640, mean, var);
  final_k<<<N_E3, 128, 0, stream>>>(yhat, mean, var, bno_g, bno_b, ea3, Ww, Wb, out);
}

// Round 3
// 302.955 us; speedup vs baseline: 19.8005x; 1.3479x over previous
//
#include <hip/hip_runtime.h>
#include <hip/hip_bf16.h>
#include <math.h>

#define N_NODES 8192
#define N_EDGES 16384
#define N_E3    1024
#define NGRAPH  256
#define NPG     32
#define SLOPE   (11.0f/48.0f)
#define BN_EPS  1e-5f

__device__ __forceinline__ float rrelu(float v){ return v >= 0.f ? v : SLOPE*v; }
__device__ __forceinline__ float sigm(float v){ return 1.f/(1.f+__expf(-v)); }

// ================= generic tiled GEMM body =================
// C[M,J] = act(preA(A)[M,K] @ W^T + bias).  WT: W[J,K] vs [K,J].
// PRE: 0 none; 1 scatter-mean prep: A=rrelu(A/max(q0[row],1)+q1[k]); 2 BN: (A-q0[k])*rsqrt(q1[k]+eps)*q2[k]+q3[k]
#define BK 32
template<bool WT, int ACT, int PRE>
__device__ __forceinline__ void gemm_body(float As[BK][68], float Ws[BK][68],
    const float* __restrict__ A, const float* __restrict__ W, const float* __restrict__ bias,
    const float* __restrict__ q0, const float* __restrict__ q1,
    const float* __restrict__ q2, const float* __restrict__ q3,
    float* __restrict__ C, int M, int K, int J, int blk) {
  int t = threadIdx.x;
  int jt = J >> 6;
  int bm = blk / jt, bj = blk % jt;
  int n0 = bm << 6, j0 = bj << 6;
  int tx = t & 15, ty = t >> 4;
  int lr = t >> 2, lq = t & 3;
  float acc[4][4] = {};

  for (int k0 = 0; k0 < K; k0 += BK) {
    { // A tile -> As[kk][n]
      int row = n0 + lr;
      const float* src = A + (size_t)row * K + k0;
      float4 v0 = *(const float4*)(src + lq*4);
      float4 v1 = *(const float4*)(src + lq*4 + 16);
      if (PRE == 1) {
        float dn = 1.f / fmaxf(q0[row], 1.f);
        int kb = k0 + lq*4;
        v0.x = rrelu(v0.x*dn + q1[kb+0]);  v0.y = rrelu(v0.y*dn + q1[kb+1]);
        v0.z = rrelu(v0.z*dn + q1[kb+2]);  v0.w = rrelu(v0.w*dn + q1[kb+3]);
        v1.x = rrelu(v1.x*dn + q1[kb+16]); v1.y = rrelu(v1.y*dn + q1[kb+17]);
        v1.z = rrelu(v1.z*dn + q1[kb+18]); v1.w = rrelu(v1.w*dn + q1[kb+19]);
      } else if (PRE == 2) {
        int kb = k0 + lq*4;
        v0.x = (v0.x-q0[kb+0])*rsqrtf(q1[kb+0]+BN_EPS)*q2[kb+0]+q3[kb+0];
        v0.y = (v0.y-q0[kb+1])*rsqrtf(q1[kb+1]+BN_EPS)*q2[kb+1]+q3[kb+1];
        v0.z = (v0.z-q0[kb+2])*rsqrtf(q1[kb+2]+BN_EPS)*q2[kb+2]+q3[kb+2];
        v0.w = (v0.w-q0[kb+3])*rsqrtf(q1[kb+3]+BN_EPS)*q2[kb+3]+q3[kb+3];
        v1.x = (v1.x-q0[kb+16])*rsqrtf(q1[kb+16]+BN_EPS)*q2[kb+16]+q3[kb+16];
        v1.y = (v1.y-q0[kb+17])*rsqrtf(q1[kb+17]+BN_EPS)*q2[kb+17]+q3[kb+17];
        v1.z = (v1.z-q0[kb+18])*rsqrtf(q1[kb+18]+BN_EPS)*q2[kb+18]+q3[kb+18];
        v1.w = (v1.w-q0[kb+19])*rsqrtf(q1[kb+19]+BN_EPS)*q2[kb+19]+q3[kb+19];
      }
      As[lq*4+0][lr]=v0.x; As[lq*4+1][lr]=v0.y; As[lq*4+2][lr]=v0.z; As[lq*4+3][lr]=v0.w;
      As[lq*4+16][lr]=v1.x; As[lq*4+17][lr]=v1.y; As[lq*4+18][lr]=v1.z; As[lq*4+19][lr]=v1.w;
    }
    if (WT) {
      const float* src = W + (size_t)(j0 + lr) * K + k0;
      float4 v0 = *(const float4*)(src + lq*4);
      float4 v1 = *(const float4*)(src + lq*4 + 16);
      Ws[lq*4+0][lr]=v0.x; Ws[lq*4+1][lr]=v0.y; Ws[lq*4+2][lr]=v0.z; Ws[lq*4+3][lr]=v0.w;
      Ws[lq*4+16][lr]=v1.x; Ws[lq*4+17][lr]=v1.y; Ws[lq*4+18][lr]=v1.z; Ws[lq*4+19][lr]=v1.w;
    } else {
      int wr = t >> 3, wq = t & 7;
      const float* src = W + (size_t)(k0 + wr) * J + j0;
      *(float4*)&Ws[wr][wq*4]      = *(const float4*)(src + wq*4);
      *(float4*)&Ws[wr][wq*4 + 32] = *(const float4*)(src + wq*4 + 32);
    }
    __syncthreads();
    #pragma unroll
    for (int kk = 0; kk < BK; kk++) {
      float4 a = *(const float4*)&As[kk][ty*4];
      float4 w = *(const float4*)&Ws[kk][tx*4];
      acc[0][0]+=a.x*w.x; acc[0][1]+=a.x*w.y; acc[0][2]+=a.x*w.z; acc[0][3]+=a.x*w.w;
      acc[1][0]+=a.y*w.x; acc[1][1]+=a.y*w.y; acc[1][2]+=a.y*w.z; acc[1][3]+=a.y*w.w;
      acc[2][0]+=a.z*w.x; acc[2][1]+=a.z*w.y; acc[2][2]+=a.z*w.z; acc[2][3]+=a.z*w.w;
      acc[3][0]+=a.w*w.x; acc[3][1]+=a.w*w.y; acc[3][2]+=a.w*w.z; acc[3][3]+=a.w*w.w;
    }
    __syncthreads();
  }
  int j = j0 + tx*4;
  float4 bv = bias ? *(const float4*)&bias[j] : make_float4(0.f,0.f,0.f,0.f);
  #pragma unroll
  for (int r = 0; r < 4; r++) {
    float4 o;
    o.x = acc[r][0] + bv.x; o.y = acc[r][1] + bv.y;
    o.z = acc[r][2] + bv.z; o.w = acc[r][3] + bv.w;
    if (ACT == 1) { o.x = rrelu(o.x); o.y = rrelu(o.y); o.z = rrelu(o.z); o.w = rrelu(o.w); }
    *(float4*)&C[(size_t)(n0 + ty*4 + r) * J + j] = o;
  }
}

template<bool WT, int ACT, int PRE>
__global__ __launch_bounds__(256) void gemm_k(const float* __restrict__ A,
    const float* __restrict__ W, const float* __restrict__ bias,
    const float* __restrict__ q0, const float* __restrict__ q1,
    const float* __restrict__ q2, const float* __restrict__ q3,
    float* __restrict__ C, int M, int K, int J) {
  __shared__ float As[BK][68], Ws[BK][68];
  gemm_body<WT,ACT,PRE>(As, Ws, A, W, bias, q0, q1, q2, q3, C, M, K, J, blockIdx.x);
}

// dual GEMM: side0 = gi (PRE0), side1 = gh
template<bool WT0, int PRE0, bool WT1, int PRE1>
__global__ __launch_bounds__(256) void gemm2_k(
    const float* __restrict__ A0, const float* __restrict__ W0, const float* __restrict__ b0,
    const float* __restrict__ q00, const float* __restrict__ q01,
    float* __restrict__ C0, int M0, int K0, int J0, int nblk0,
    const float* __restrict__ A1, const float* __restrict__ W1, const float* __restrict__ b1,
    float* __restrict__ C1, int M1, int K1, int J1) {
  __shared__ float As[BK][68], Ws[BK][68];
  if ((int)blockIdx.x < nblk0)
    gemm_body<WT0,0,PRE0>(As, Ws, A0, W0, b0, q00, q01, nullptr, nullptr, C0, M0, K0, J0, blockIdx.x);
  else
    gemm_body<WT1,0,PRE1>(As, Ws, A1, W1, b1, nullptr, nullptr, nullptr, nullptr, C1, M1, K1, J1, blockIdx.x - nblk0);
}

// ================= small kernels =================
__global__ void bn_stats_k(const float* __restrict__ X, int nrow, int F,
                           float* __restrict__ mean, float* __restrict__ var) {
  int f = blockIdx.x, t = threadIdx.x;
  __shared__ float s1[256], s2[256];
  float a = 0.f, b = 0.f;
  for (int n = t; n < nrow; n += 256) {
    float v = X[(size_t)n * F + f];
    a += v; b += v * v;
  }
  s1[t] = a; s2[t] = b; __syncthreads();
  for (int w = 128; w > 0; w >>= 1) {
    if (t < w) { s1[t] += s1[t+w]; s2[t] += s2[t+w]; }
    __syncthreads();
  }
  if (t == 0) {
    float m = s1[0] / (float)nrow;
    mean[f] = m;
    var[f]  = s2[0] / (float)nrow - m * m;
  }
}

__global__ void node_embed_k(const float* __restrict__ x,
                             const float* __restrict__ mean, const float* __restrict__ var,
                             const float* __restrict__ g, const float* __restrict__ b,
                             const float* __restrict__ Wn, const float* __restrict__ bnode,
                             float* __restrict__ out) {
  int idx = blockIdx.x * blockDim.x + threadIdx.x;
  if (idx >= N_NODES * 64) return;
  int n = idx >> 6, o = idx & 63;
  float acc = bnode[o];
  #pragma unroll
  for (int i = 0; i < 8; i++) {
    float xn = (x[n*8+i] - mean[i]) * rsqrtf(var[i] + BN_EPS) * g[i] + b[i];
    acc += xn * Wn[i*64 + o];
  }
  out[idx] = rrelu(acc);
}

__global__ void edge_embed_k(const float* __restrict__ eattr,
                             const float* __restrict__ We, const float* __restrict__ be,
                             float* __restrict__ ea) {
  int idx = blockIdx.x * blockDim.x + threadIdx.x;
  if (idx >= N_EDGES * 12) return;
  int e = idx / 12, j = idx - e * 12;
  float acc = be[j];
  #pragma unroll
  for (int k = 0; k < 19; k++) acc += eattr[e*19+k] * We[k*12 + j];
  ea[idx] = rrelu(acc);
}

// packs: Wz1 [768][64]; Wcat [384][512]; W2f [128][1024]
__global__ void pack_k(const float* __restrict__ Wnn1, const float* __restrict__ Ws_ih,
                       const float* __restrict__ Ws_hh, const float* __restrict__ Wnn2,
                       float* __restrict__ Wz1, float* __restrict__ Wcat, float* __restrict__ W2f) {
  int idx = blockIdx.x * 256 + threadIdx.x;
  if (idx < 49152) {
    int jj = idx >> 6, i = idx & 63;
    int k = jj >> 6, o = jj & 63;
    Wz1[idx] = Wnn1[k*4096 + i*64 + o];
  }
  if (idx < 196608) {
    int i = idx >> 9, j = idx & 511;
    Wcat[idx] = (i < 256) ? Ws_ih[(size_t)j*256 + i] : Ws_hh[(size_t)j*128 + (i-256)];
  }
  if (idx < 131072) {
    int i = idx >> 10, r = idx & 1023;
    int k = r >> 7, o = r & 127;
    W2f[idx] = Wnn2[k*16384 + i*128 + o];
  }
}

// per-dst edge counts (iteration-invariant)
__global__ void cnt_k(const int* __restrict__ ei, const int* __restrict__ ei3,
                      float* __restrict__ cnt1, float* __restrict__ cnt2) {
  int idx = blockIdx.x * 256 + threadIdx.x;
  if (idx < N_EDGES) atomicAdd(&cnt1[ei[N_EDGES + idx]], 1.0f);
  if (idx < N_E3) {
    atomicAdd(&cnt2[ei3[N_E3 + idx]], 1.0f);
    atomicAdd(&cnt2[ei3[idx]], 1.0f);
  }
}

// conv1: msg[e,o] = sum_k ea[e,k] * Z[src, k*64+o]; scatter to sbuf
__global__ void conv1_msg_k(const float* __restrict__ Z, const int* __restrict__ ei,
                            const float* __restrict__ ea, float* __restrict__ sbuf) {
  int idx = blockIdx.x * 256 + threadIdx.x;
  if (idx >= N_EDGES * 64) return;
  int e = idx >> 6, o = idx & 63;
  int src = ei[e], dst = ei[N_EDGES + e];
  const float* z = Z + (size_t)src * 768 + o;
  float msg = 0.f;
  #pragma unroll
  for (int k = 0; k < 12; k++) msg += ea[e*12 + k] * z[k*64];
  atomicAdd(&sbuf[dst*64 + o], msg);
}

// gather src rows for conv2 GEMM (symmetrized edges)
__global__ void gather_k(const float* __restrict__ feat, const int* __restrict__ ei3,
                         float* __restrict__ Xg) {
  int idx = blockIdx.x * 256 + threadIdx.x;
  if (idx >= 2*N_E3*128) return;
  int e = idx >> 7, o = idx & 127;
  int eb = (e < N_E3) ? e : e - N_E3;
  int src = (e < N_E3) ? ei3[eb] : ei3[N_E3 + eb];
  Xg[idx] = feat[(size_t)src*128 + o];
}

// conv2: msg[e,o] = sum_k ea3[e,k] * Zg[e, k*128+o]; scatter
__global__ void conv2_msg_k(const float* __restrict__ Zg, const int* __restrict__ ei3,
                            const float* __restrict__ ea3, float* __restrict__ sbuf) {
  int idx = blockIdx.x * 256 + threadIdx.x;
  if (idx >= 2*N_E3*128) return;
  int e = idx >> 7, o = idx & 127;
  int eb = (e < N_E3) ? e : e - N_E3;
  int dst = (e < N_E3) ? ei3[N_E3 + eb] : ei3[eb];
  const float* z = Zg + (size_t)e*1024 + o;
  float msg = 0.f;
  #pragma unroll
  for (int k = 0; k < 8; k++) msg += ea3[eb*8 + k] * z[k*128];
  atomicAdd(&sbuf[dst*128 + o], msg);
}

// GRU combine: h = (1-z)*nn + z*h
template<int LOGH>
__global__ void gru_combine_k(const float* __restrict__ gi, const float* __restrict__ gh,
                              float* __restrict__ h) {
  int idx = blockIdx.x * 256 + threadIdx.x;
  const int H = 1 << LOGH;
  if (idx >= N_NODES * H) return;
  int n = idx >> LOGH, f = idx & (H - 1);
  const float* gin = gi + (size_t)n * 3 * H;
  const float* ghn = gh + (size_t)n * 3 * H;
  float r  = sigm(gin[f]        + ghn[f]);
  float z  = sigm(gin[H + f]    + ghn[H + f]);
  float nn = tanhf(gin[2*H + f] + r * ghn[2*H + f]);
  h[idx] = (1.f - z) * nn + z * h[idx];
}

// ---------- Set2Set: 512 threads per graph, one thread per gate output ----------
__global__ __launch_bounds__(512) void set2set_k(const float* __restrict__ x,
    const float* __restrict__ Wcat,
    const float* __restrict__ bs_ih, const float* __restrict__ bs_hh,
    float* __restrict__ qpool) {
  int g = blockIdx.x, t = threadIdx.x;   // 512 threads
  __shared__ float in[384];   // [q_h(128) | q_r(128) | h(128)]
  __shared__ float cbuf[128], gbuf[512], abuf[NPG];
  if (t < 384) in[t] = 0.f;
  if (t < 128) cbuf[t] = 0.f;
  __syncthreads();
  for (int step = 0; step < 3; step++) {
    // gates: thread t computes gate output j=t over 384 inputs
    float a0=0.f, a1=0.f, a2=0.f, a3=0.f;
    const float* wp = Wcat + t;
    #pragma unroll 2
    for (int i = 0; i < 384; i += 4) {
      a0 += in[i]   * wp[(i)  *512];
      a1 += in[i+1] * wp[(i+1)*512];
      a2 += in[i+2] * wp[(i+2)*512];
      a3 += in[i+3] * wp[(i+3)*512];
    }
    gbuf[t] = a0 + a1 + a2 + a3 + bs_ih[t] + bs_hh[t];
    __syncthreads();
    if (t < 128) {  // LSTM update (gate order i,f,g,o)
      float ci = sigm(gbuf[128+t]) * cbuf[t] + sigm(gbuf[t]) * tanhf(gbuf[256+t]);
      float hi = sigm(gbuf[384+t]) * tanhf(ci);
      cbuf[t] = ci; in[256+t] = hi;
    }
    __syncthreads();
    { // attention scores: 32 nodes x 16 threads, each covers 8 features
      int node = t >> 4, s = t & 15;
      const float* xr = x + (size_t)(g*NPG + node)*128 + s*8;
      float p = 0.f;
      #pragma unroll
      for (int u = 0; u < 8; u++) p += xr[u] * in[256 + s*8 + u];
      p += __shfl_down(p, 8, 16); p += __shfl_down(p, 4, 16);
      p += __shfl_down(p, 2, 16); p += __shfl_down(p, 1, 16);
      if (s == 0) gbuf[node] = p;
    }
    __syncthreads();
    if (t < NPG) {  // softmax over the 32 nodes (one half-wave)
      float e = gbuf[t];
      float mx = e;
      for (int o = 16; o > 0; o >>= 1) mx = fmaxf(mx, __shfl_xor(mx, o, 32));
      float ex = __expf(e - mx);
      float den = ex;
      for (int o = 16; o > 0; o >>= 1) den += __shfl_xor(den, o, 32);
      abuf[t] = ex / den;
    }
    __syncthreads();
    if (t < 128) {  // weighted readout + next q_star
      float r = 0.f;
      const float* xg = x + (size_t)(g*NPG)*128 + t;
      #pragma unroll 8
      for (int nn = 0; nn < NPG; nn++) r += abuf[nn] * xg[nn*128];
      in[t] = in[256+t];
      in[128+t] = r;
    }
    __syncthreads();
  }
  if (t < 256) qpool[g*256 + t] = in[t];
}

__global__ void yhat_k(const float* __restrict__ feat, const int* __restrict__ ei3,
                       const int* __restrict__ batch, const float* __restrict__ qpool,
                       float* __restrict__ yhat) {
  int idx = blockIdx.x * blockDim.x + threadIdx.x;
  if (idx >= N_E3 * 640) return;
  int e = idx / 640, j = idx - e * 640;
  int s0 = ei3[e], s1 = ei3[N_E3 + e];
  float v;
  if (j < 128)      { v = 0.5f * (feat[s0*128+j] + feat[s1*128+j]); }
  else if (j < 256) { int jj = j-128; v = feat[s0*128+jj] * feat[s1*128+jj]; }
  else if (j < 384) { int jj = j-256; float d = feat[s0*128+jj] - feat[s1*128+jj]; v = d*d; }
  else              { int cbi = batch[s0]; v = qpool[cbi*256 + (j-384)]; }
  yhat[idx] = v;
}

__global__ void final_k(const float* __restrict__ yhat,
                        const float* __restrict__ mean, const float* __restrict__ var,
                        const float* __restrict__ g, const float* __restrict__ b,
                        const float* __restrict__ ea3,
                        const float* __restrict__ Ww, const float* __restrict__ Wb,
                        float* __restrict__ out) {
  int e = blockIdx.x, t = threadIdx.x;  // 128 threads
  __shared__ float red[128];
  float av[8];
  #pragma unroll
  for (int k = 0; k < 8; k++) av[k] = ea3[e*8 + k];
  float acc = 0.f;
  for (int j = t; j < 640; j += 128) {
    float yn = (yhat[(size_t)e*640 + j] - mean[j]) * rsqrtf(var[j] + BN_EPS) * g[j] + b[j];
    float wj = 0.f;
    #pragma unroll
    for (int k = 0; k < 8; k++) wj += av[k] * Ww[k*640 + j];
    acc += yn * wj;
  }
  red[t] = acc; __syncthreads();
  for (int w = 64; w > 0; w >>= 1) {
    if (t < w) red[t] += red[t+w];
    __syncthreads();
  }
  if (t == 0) {
    float bb = 0.f;
    #pragma unroll
    for (int k = 0; k < 8; k++) bb += av[k] * Wb[k];
    out[e] = red[0] + bb;
  }
}

extern "C" void kernel_launch(void* const* d_in, const int* in_sizes, int n_in,
                              void* d_out, int out_size, void* d_ws, size_t ws_size,
                              hipStream_t stream) {
  const float* x      = (const float*)d_in[0];
  const int*   ei     = (const int*)  d_in[1];
  const float* eattr  = (const float*)d_in[2];
  const int*   ei3    = (const int*)  d_in[3];
  const float* ea3    = (const float*)d_in[4];
  const int*   batch  = (const int*)  d_in[5];
  const float* bnx_g  = (const float*)d_in[6];
  const float* bnx_b  = (const float*)d_in[7];
  const float* Wn     = (const float*)d_in[8];
  const float* bnode  = (const float*)d_in[9];
  const float* We     = (const float*)d_in[10];
  const float* be     = (const float*)d_in[11];
  const float* Wnn1   = (const float*)d_in[12];
  const float* bias1  = (const float*)d_in[13];
  const float* Wih1   = (const float*)d_in[14];
  const float* Whh1   = (const float*)d_in[15];
  const float* bih1   = (const float*)d_in[16];
  const float* bhh1   = (const float*)d_in[17];
  const float* bnc_g  = (const float*)d_in[18];
  const float* bnc_b  = (const float*)d_in[19];
  const float* Wc1    = (const float*)d_in[20];
  const float* bc1    = (const float*)d_in[21];
  const float* Wc2    = (const float*)d_in[22];
  const float* bc2    = (const float*)d_in[23];
  const float* Wnn2   = (const float*)d_in[24];
  const float* bias2  = (const float*)d_in[25];
  const float* Wih2   = (const float*)d_in[26];
  const float* Whh2   = (const float*)d_in[27];
  const float* bih2   = (const float*)d_in[28];
  const float* bhh2   = (const float*)d_in[29];
  const float* Ws_ih  = (const float*)d_in[30];
  const float* Ws_hh  = (const float*)d_in[31];
  const float* bs_ih  = (const float*)d_in[32];
  const float* bs_hh  = (const float*)d_in[33];
  const float* bno_g  = (const float*)d_in[34];
  const float* bno_b  = (const float*)d_in[35];
  const float* Ww     = (const float*)d_in[36];
  const float* Wb     = (const float*)d_in[37];
  float* out = (float*)d_out;

  // workspace carve-up (floats)
  float* W = (float*)d_ws;
  size_t off = 0;
  float* Wz1   = W + off; off += 49152;                  // [768][64]
  float* Wcat  = W + off; off += 196608;                 // [384][512]
  float* W2f   = W + off; off += 131072;                 // [128][1024]
  float* ea12  = W + off; off += (size_t)N_EDGES * 12;
  float* nodeA = W + off; off += (size_t)N_NODES * 64;
  float* sbuf  = W + off; off += (size_t)N_NODES * 128;
  float* cnt1  = W + off; off += (size_t)N_NODES;
  float* cnt2  = W + off; off += (size_t)N_NODES;
  float* y1    = W + off; off += (size_t)N_NODES * 128;
  float* nodeB = W + off; off += (size_t)N_NODES * 128;
  float* Z     = W + off; off += (size_t)N_NODES * 768;  // aliased: gates / Zg / Xg
  float* qpool = W + off; off += (size_t)NGRAPH * 256;
  float* yhat  = W + off; off += (size_t)N_E3 * 640;
  float* mean  = W + off; off += 640;
  float* var   = W + off; off += 640;
  (void)off; (void)ws_size; (void)in_sizes; (void)n_in; (void)out_size;

  float* gatesI1 = Z;                          // [8192,192]
  float* gatesH1 = Z + (size_t)N_NODES * 192;
  float* gatesI2 = Z;                          // [8192,384]
  float* gatesH2 = Z + (size_t)N_NODES * 384;
  float* Zg      = Z;                          // [2048,1024] (dead before gates written)
  float* Xg      = Z + 2097152;                // [2048,128]

  // 0. one-time packs + counts
  pack_k<<<768, 256, 0, stream>>>(Wnn1, Ws_ih, Ws_hh, Wnn2, Wz1, Wcat, W2f);
  hipMemsetAsync(cnt1, 0, 2*(size_t)N_NODES*sizeof(float), stream);
  cnt_k<<<(N_EDGES+255)/256, 256, 0, stream>>>(ei, ei3, cnt1, cnt2);

  // 1. node embed + edge embed
  bn_stats_k<<<8, 256, 0, stream>>>(x, N_NODES, 8, mean, var);
  node_embed_k<<<(N_NODES*64 + 255)/256, 256, 0, stream>>>(x, mean, var, bnx_g, bnx_b, Wn, bnode, nodeA);
  edge_embed_k<<<(N_EDGES*12 + 255)/256, 256, 0, stream>>>(eattr, We, be, ea12);

  // 2. layer-1 x2: Z GEMM -> scatter -> dual gate GEMM (m_prep fused) -> combine
  for (int it = 0; it < 2; it++) {
    gemm_k<true,0,0><<<(N_NODES/64)*(768/64), 256, 0, stream>>>(nodeA, Wz1, nullptr,
        nullptr, nullptr, nullptr, nullptr, Z, N_NODES, 64, 768);
    hipMemsetAsync(sbuf, 0, (size_t)N_NODES*64*sizeof(float), stream);
    conv1_msg_k<<<(N_EDGES*64)/256, 256, 0, stream>>>(Z, ei, ea12, sbuf);
    gemm2_k<true,1,true,0><<<768, 256, 0, stream>>>(
        sbuf,  Wih1, bih1, cnt1, bias1, gatesI1, N_NODES, 64, 192, 384,
        nodeA, Whh1, bhh1,               gatesH1, N_NODES, 64, 192);
    gru_combine_k<6><<<(N_NODES*64)/256, 256, 0, stream>>>(gatesI1, gatesH1, nodeA);
  }

  // 3. BN (fused into fc1) + FC1 + FC2
  bn_stats_k<<<64, 256, 0, stream>>>(nodeA, N_NODES, 64, mean, var);
  gemm_k<false,1,2><<<(N_NODES/64)*(128/64), 256, 0, stream>>>(nodeA, Wc1, bc1,
      mean, var, bnc_g, bnc_b, y1, N_NODES, 64, 128);
  gemm_k<false,1,0><<<(N_NODES/64)*(128/64), 256, 0, stream>>>(y1, Wc2, bc2,
      nullptr, nullptr, nullptr, nullptr, nodeB, N_NODES, 128, 128);

  // 4. layer-2 x2: gather -> Zg GEMM -> scatter -> dual gate GEMM -> combine
  for (int it = 0; it < 2; it++) {
    gather_k<<<(2*N_E3*128)/256, 256, 0, stream>>>(nodeB, ei3, Xg);
    gemm_k<false,0,0><<<(2*N_E3/64)*(1024/64), 256, 0, stream>>>(Xg, W2f, nullptr,
        nullptr, nullptr, nullptr, nullptr, Zg, 2*N_E3, 128, 1024);
    hipMemsetAsync(sbuf, 0, (size_t)N_NODES*128*sizeof(float), stream);
    conv2_msg_k<<<(2*N_E3*128)/256, 256, 0, stream>>>(Zg, ei3, ea3, sbuf);
    gemm2_k<true,1,true,0><<<1536, 256, 0, stream>>>(
        sbuf,  Wih2, bih2, cnt2, bias2, gatesI2, N_NODES, 128, 384, 768,
        nodeB, Whh2, bhh2,               gatesH2, N_NODES, 128, 384);
    gru_combine_k<7><<<(N_NODES*128)/256, 256, 0, stream>>>(gatesI2, gatesH2, nodeB);
  }

  // 5. set2set
  set2set_k<<<NGRAPH, 512, 0, stream>>>(nodeB, Wcat, bs_ih, bs_hh, qpool);

  // 6. yhat + BN + weighted sum
  yhat_k<<<(N_E3*640 + 255)/256, 256, 0, stream>>>(nodeB, ei3, batch, qpool, yhat);
  bn_stats_k<<<640, 256, 0, stream>>>(yhat, N_E3, 640, mean, var);
  final_k<<<N_E3, 128, 0, stream>>>(yhat, mean, var, bno_g, bno_b, ea3, Ww, Wb, out);
}

// Round 4
// 266.214 us; speedup vs baseline: 22.5331x; 1.1380x over previous
//
#include <hip/hip_runtime.h>
#include <hip/hip_bf16.h>
#include <math.h>

#define N_NODES 8192
#define N_EDGES 16384
#define N_E3    1024
#define NGRAPH  256
#define NPG     32
#define SLOPE   (11.0f/48.0f)
#define BN_EPS  1e-5f

__device__ __forceinline__ float rrelu(float v){ return v >= 0.f ? v : SLOPE*v; }
__device__ __forceinline__ float sigm(float v){ return 1.f/(1.f+__expf(-v)); }

// ================= generic tiled GEMM body =================
// C[M,J] = act(preA(A)[M,K] @ W^T + bias).  WT: W[J,K] vs [K,J].
// PRE: 0 none; 1 scatter-mean prep: A=rrelu(A/max(q0[row],1)+q1[k]); 2 BN
// rowidx: optional gather of A rows.
#define BK 32
template<bool WT, int ACT, int PRE>
__device__ __forceinline__ void gemm_body(float As[BK][68], float Ws[BK][68],
    const float* __restrict__ A, const float* __restrict__ W, const float* __restrict__ bias,
    const float* __restrict__ q0, const float* __restrict__ q1,
    const float* __restrict__ q2, const float* __restrict__ q3,
    const int* __restrict__ rowidx,
    float* __restrict__ C, int M, int K, int J, int blk) {
  int t = threadIdx.x;
  int jt = J >> 6;
  int bm = blk / jt, bj = blk % jt;
  int n0 = bm << 6, j0 = bj << 6;
  int tx = t & 15, ty = t >> 4;
  int lr = t >> 2, lq = t & 3;
  float acc[4][4] = {};

  int arow = n0 + lr;
  if (rowidx) arow = rowidx[arow];

  for (int k0 = 0; k0 < K; k0 += BK) {
    { // A tile -> As[kk][n]
      const float* src = A + (size_t)arow * K + k0;
      float4 v0 = *(const float4*)(src + lq*4);
      float4 v1 = *(const float4*)(src + lq*4 + 16);
      if (PRE == 1) {
        float dn = 1.f / fmaxf(q0[n0 + lr], 1.f);
        int kb = k0 + lq*4;
        v0.x = rrelu(v0.x*dn + q1[kb+0]);  v0.y = rrelu(v0.y*dn + q1[kb+1]);
        v0.z = rrelu(v0.z*dn + q1[kb+2]);  v0.w = rrelu(v0.w*dn + q1[kb+3]);
        v1.x = rrelu(v1.x*dn + q1[kb+16]); v1.y = rrelu(v1.y*dn + q1[kb+17]);
        v1.z = rrelu(v1.z*dn + q1[kb+18]); v1.w = rrelu(v1.w*dn + q1[kb+19]);
      } else if (PRE == 2) {
        int kb = k0 + lq*4;
        v0.x = (v0.x-q0[kb+0])*rsqrtf(q1[kb+0]+BN_EPS)*q2[kb+0]+q3[kb+0];
        v0.y = (v0.y-q0[kb+1])*rsqrtf(q1[kb+1]+BN_EPS)*q2[kb+1]+q3[kb+1];
        v0.z = (v0.z-q0[kb+2])*rsqrtf(q1[kb+2]+BN_EPS)*q2[kb+2]+q3[kb+2];
        v0.w = (v0.w-q0[kb+3])*rsqrtf(q1[kb+3]+BN_EPS)*q2[kb+3]+q3[kb+3];
        v1.x = (v1.x-q0[kb+16])*rsqrtf(q1[kb+16]+BN_EPS)*q2[kb+16]+q3[kb+16];
        v1.y = (v1.y-q0[kb+17])*rsqrtf(q1[kb+17]+BN_EPS)*q2[kb+17]+q3[kb+17];
        v1.z = (v1.z-q0[kb+18])*rsqrtf(q1[kb+18]+BN_EPS)*q2[kb+18]+q3[kb+18];
        v1.w = (v1.w-q0[kb+19])*rsqrtf(q1[kb+19]+BN_EPS)*q2[kb+19]+q3[kb+19];
      }
      As[lq*4+0][lr]=v0.x; As[lq*4+1][lr]=v0.y; As[lq*4+2][lr]=v0.z; As[lq*4+3][lr]=v0.w;
      As[lq*4+16][lr]=v1.x; As[lq*4+17][lr]=v1.y; As[lq*4+18][lr]=v1.z; As[lq*4+19][lr]=v1.w;
    }
    if (WT) {
      const float* src = W + (size_t)(j0 + lr) * K + k0;
      float4 v0 = *(const float4*)(src + lq*4);
      float4 v1 = *(const float4*)(src + lq*4 + 16);
      Ws[lq*4+0][lr]=v0.x; Ws[lq*4+1][lr]=v0.y; Ws[lq*4+2][lr]=v0.z; Ws[lq*4+3][lr]=v0.w;
      Ws[lq*4+16][lr]=v1.x; Ws[lq*4+17][lr]=v1.y; Ws[lq*4+18][lr]=v1.z; Ws[lq*4+19][lr]=v1.w;
    } else {
      int wr = t >> 3, wq = t & 7;
      const float* src = W + (size_t)(k0 + wr) * J + j0;
      *(float4*)&Ws[wr][wq*4]      = *(const float4*)(src + wq*4);
      *(float4*)&Ws[wr][wq*4 + 32] = *(const float4*)(src + wq*4 + 32);
    }
    __syncthreads();
    #pragma unroll
    for (int kk = 0; kk < BK; kk++) {
      float4 a = *(const float4*)&As[kk][ty*4];
      float4 w = *(const float4*)&Ws[kk][tx*4];
      acc[0][0]+=a.x*w.x; acc[0][1]+=a.x*w.y; acc[0][2]+=a.x*w.z; acc[0][3]+=a.x*w.w;
      acc[1][0]+=a.y*w.x; acc[1][1]+=a.y*w.y; acc[1][2]+=a.y*w.z; acc[1][3]+=a.y*w.w;
      acc[2][0]+=a.z*w.x; acc[2][1]+=a.z*w.y; acc[2][2]+=a.z*w.z; acc[2][3]+=a.z*w.w;
      acc[3][0]+=a.w*w.x; acc[3][1]+=a.w*w.y; acc[3][2]+=a.w*w.z; acc[3][3]+=a.w*w.w;
    }
    __syncthreads();
  }
  int j = j0 + tx*4;
  float4 bv = bias ? *(const float4*)&bias[j] : make_float4(0.f,0.f,0.f,0.f);
  #pragma unroll
  for (int r = 0; r < 4; r++) {
    float4 o;
    o.x = acc[r][0] + bv.x; o.y = acc[r][1] + bv.y;
    o.z = acc[r][2] + bv.z; o.w = acc[r][3] + bv.w;
    if (ACT == 1) { o.x = rrelu(o.x); o.y = rrelu(o.y); o.z = rrelu(o.z); o.w = rrelu(o.w); }
    *(float4*)&C[(size_t)(n0 + ty*4 + r) * J + j] = o;
  }
}

// gemm with optional row-gather + trailing zero-blocks (fold memset)
template<bool WT, int ACT, int PRE>
__global__ __launch_bounds__(256) void gemm_k(const float* __restrict__ A,
    const float* __restrict__ W, const float* __restrict__ bias,
    const float* __restrict__ q0, const float* __restrict__ q1,
    const float* __restrict__ q2, const float* __restrict__ q3,
    const int* __restrict__ rowidx,
    float* __restrict__ C, int M, int K, int J,
    int nblk, float* __restrict__ zptr, int zcount) {
  int blk = blockIdx.x;
  if (blk >= nblk) {
    int zb = blk - nblk;
    float4 z4 = make_float4(0.f,0.f,0.f,0.f);
    for (int i = zb*256 + (int)threadIdx.x; i*4 < zcount; i += 16*256)
      ((float4*)zptr)[i] = z4;
    return;
  }
  __shared__ float As[BK][68], Ws[BK][68];
  gemm_body<WT,ACT,PRE>(As, Ws, A, W, bias, q0, q1, q2, q3, rowidx, C, M, K, J, blk);
}

// dual GEMM: side0 = gi (PRE0), side1 = gh
template<bool WT0, int PRE0, bool WT1, int PRE1>
__global__ __launch_bounds__(256) void gemm2_k(
    const float* __restrict__ A0, const float* __restrict__ W0, const float* __restrict__ b0,
    const float* __restrict__ q00, const float* __restrict__ q01,
    float* __restrict__ C0, int M0, int K0, int J0, int nblk0,
    const float* __restrict__ A1, const float* __restrict__ W1, const float* __restrict__ b1,
    float* __restrict__ C1, int M1, int K1, int J1) {
  __shared__ float As[BK][68], Ws[BK][68];
  if ((int)blockIdx.x < nblk0)
    gemm_body<WT0,0,PRE0>(As, Ws, A0, W0, b0, q00, q01, nullptr, nullptr, nullptr, C0, M0, K0, J0, blockIdx.x);
  else
    gemm_body<WT1,0,PRE1>(As, Ws, A1, W1, b1, nullptr, nullptr, nullptr, nullptr, nullptr, C1, M1, K1, J1, blockIdx.x - nblk0);
}

// ================= small kernels =================
__global__ void bn_stats_k(const float* __restrict__ X, int nrow, int F,
                           float* __restrict__ mean, float* __restrict__ var) {
  int f = blockIdx.x, t = threadIdx.x;
  __shared__ float s1[256], s2[256];
  float a = 0.f, b = 0.f;
  for (int n = t; n < nrow; n += 256) {
    float v = X[(size_t)n * F + f];
    a += v; b += v * v;
  }
  s1[t] = a; s2[t] = b; __syncthreads();
  for (int w = 128; w > 0; w >>= 1) {
    if (t < w) { s1[t] += s1[t+w]; s2[t] += s2[t+w]; }
    __syncthreads();
  }
  if (t == 0) {
    float m = s1[0] / (float)nrow;
    mean[f] = m;
    var[f]  = s2[0] / (float)nrow - m * m;
  }
}

// merged node + edge embed
__global__ void embed_k(const float* __restrict__ x,
                        const float* __restrict__ mean, const float* __restrict__ var,
                        const float* __restrict__ g, const float* __restrict__ b,
                        const float* __restrict__ Wn, const float* __restrict__ bnode,
                        float* __restrict__ nodeA,
                        const float* __restrict__ eattr,
                        const float* __restrict__ We, const float* __restrict__ be,
                        float* __restrict__ ea12) {
  if (blockIdx.x < 2048) {
    int idx = blockIdx.x * 256 + threadIdx.x;   // N_NODES*64
    int n = idx >> 6, o = idx & 63;
    float acc = bnode[o];
    #pragma unroll
    for (int i = 0; i < 8; i++) {
      float xn = (x[n*8+i] - mean[i]) * rsqrtf(var[i] + BN_EPS) * g[i] + b[i];
      acc += xn * Wn[i*64 + o];
    }
    nodeA[idx] = rrelu(acc);
  } else {
    int idx = (blockIdx.x - 2048) * 256 + threadIdx.x;
    if (idx >= N_EDGES * 12) return;
    int e = idx / 12, j = idx - e * 12;
    float acc = be[j];
    #pragma unroll
    for (int k = 0; k < 19; k++) acc += eattr[e*19+k] * We[k*12 + j];
    ea12[idx] = rrelu(acc);
  }
}

// packs: Wz1 [768][64]; Wfold [256][512]; W2f [128][1024]; zero cnt1/cnt2
__global__ void pack_k(const float* __restrict__ Wnn1, const float* __restrict__ Ws_ih,
                       const float* __restrict__ Ws_hh, const float* __restrict__ Wnn2,
                       float* __restrict__ Wz1, float* __restrict__ Wfold, float* __restrict__ W2f,
                       float* __restrict__ cnt1, float* __restrict__ cnt2) {
  int idx = blockIdx.x * 256 + threadIdx.x;
  if (idx < 49152) {
    int jj = idx >> 6, i = idx & 63;
    int k = jj >> 6, o = jj & 63;
    Wz1[idx] = Wnn1[k*4096 + i*64 + o];
  }
  if (idx < 131072) {
    int i = idx >> 9, j = idx & 511;
    float v = Ws_ih[(size_t)j*256 + i];
    if (i < 128) v += Ws_hh[(size_t)j*128 + i];
    Wfold[idx] = v;
  }
  if (idx < 131072) {
    int i = idx >> 10, r = idx & 1023;
    int k = r >> 7, o = r & 127;
    W2f[idx] = Wnn2[k*16384 + i*128 + o];
  }
  if (idx < N_NODES) { cnt1[idx] = 0.f; cnt2[idx] = 0.f; }
}

// per-dst edge counts (iteration-invariant)
__global__ void cnt_k(const int* __restrict__ ei, const int* __restrict__ ei3,
                      float* __restrict__ cnt1, float* __restrict__ cnt2) {
  int idx = blockIdx.x * 256 + threadIdx.x;
  if (idx < N_EDGES) atomicAdd(&cnt1[ei[N_EDGES + idx]], 1.0f);
  if (idx < N_E3) {
    atomicAdd(&cnt2[ei3[N_E3 + idx]], 1.0f);
    atomicAdd(&cnt2[ei3[idx]], 1.0f);
  }
}

// conv1: msg[e,o] = sum_k ea[e,k] * Z[src, k*64+o]; scatter to sbuf
__global__ void conv1_msg_k(const float* __restrict__ Z, const int* __restrict__ ei,
                            const float* __restrict__ ea, float* __restrict__ sbuf) {
  int idx = blockIdx.x * 256 + threadIdx.x;
  if (idx >= N_EDGES * 64) return;
  int e = idx >> 6, o = idx & 63;
  int src = ei[e], dst = ei[N_EDGES + e];
  const float* z = Z + (size_t)src * 768 + o;
  float msg = 0.f;
  #pragma unroll
  for (int k = 0; k < 12; k++) msg += ea[e*12 + k] * z[k*64];
  atomicAdd(&sbuf[dst*64 + o], msg);
}

// conv2: msg[e,o] = sum_k ea3[e&1023,k] * Zg[e, k*128+o]; dst = ei3[(e+1024)&2047]
__global__ void conv2_msg_k(const float* __restrict__ Zg, const int* __restrict__ ei3,
                            const float* __restrict__ ea3, float* __restrict__ sbuf) {
  int idx = blockIdx.x * 256 + threadIdx.x;
  if (idx >= 2*N_E3*128) return;
  int e = idx >> 7, o = idx & 127;
  int eb = e & (N_E3 - 1);
  int dst = ei3[(e + N_E3) & (2*N_E3 - 1)];
  const float* z = Zg + (size_t)e*1024 + o;
  float msg = 0.f;
  #pragma unroll
  for (int k = 0; k < 8; k++) msg += ea3[eb*8 + k] * z[k*128];
  atomicAdd(&sbuf[dst*128 + o], msg);
}

// GRU combine: h = (1-z)*nn + z*h
template<int LOGH>
__global__ void gru_combine_k(const float* __restrict__ gi, const float* __restrict__ gh,
                              float* __restrict__ h) {
  int idx = blockIdx.x * 256 + threadIdx.x;
  const int H = 1 << LOGH;
  if (idx >= N_NODES * H) return;
  int n = idx >> LOGH, f = idx & (H - 1);
  const float* gin = gi + (size_t)n * 3 * H;
  const float* ghn = gh + (size_t)n * 3 * H;
  float r  = sigm(gin[f]        + ghn[f]);
  float z  = sigm(gin[H + f]    + ghn[H + f]);
  float nn = tanhf(gin[2*H + f] + r * ghn[2*H + f]);
  h[idx] = (1.f - z) * nn + z * h[idx];
}

// ---------- Set2Set v3: 1024 thr/graph, folded weights, step-0 shortcut, x in LDS ----------
__global__ __launch_bounds__(1024) void set2set_k(const float* __restrict__ x,
    const float* __restrict__ Wfold,
    const float* __restrict__ bs_ih, const float* __restrict__ bs_hh,
    float* __restrict__ qpool) {
  int g = blockIdx.x, t = threadIdx.x;   // 1024 threads
  __shared__ float xs[NPG*128];          // graph's 32 node rows (16 KB)
  __shared__ float hr[256];              // [h | r]
  __shared__ float cbuf[128];
  __shared__ float pbuf[1024];           // gate partials / scores
  __shared__ float abuf[NPG];
  *(float4*)&xs[t*4] = *(const float4*)(x + (size_t)g*NPG*128 + t*4);
  // ---- step 0: h,r = 0 -> gates are pure biases ----
  if (t < 128) {
    float gi = bs_ih[t]     + bs_hh[t];
    float gf = bs_ih[128+t] + bs_hh[128+t];
    float gg = bs_ih[256+t] + bs_hh[256+t];
    float go = bs_ih[384+t] + bs_hh[384+t];
    (void)gf;
    float c0 = sigm(gi) * tanhf(gg);          // c_prev = 0
    cbuf[t] = c0;
    hr[t] = sigm(go) * tanhf(c0);
  }
  __syncthreads();
  #pragma unroll 1
  for (int step = 0; step < 3; step++) {
    // ---- attention (uses hr[0:128] = h) ----
    {
      int node = t >> 5, s = t & 31;
      const float* xr = xs + node*128 + s*4;
      float p = xr[0]*hr[s*4] + xr[1]*hr[s*4+1] + xr[2]*hr[s*4+2] + xr[3]*hr[s*4+3];
      p += __shfl_down(p, 16, 32); p += __shfl_down(p, 8, 32);
      p += __shfl_down(p, 4, 32);  p += __shfl_down(p, 2, 32);
      p += __shfl_down(p, 1, 32);
      if (s == 0) pbuf[node] = p;
    }
    __syncthreads();
    if (t < NPG) {
      float e = pbuf[t];
      float mx = e;
      for (int o = 16; o > 0; o >>= 1) mx = fmaxf(mx, __shfl_xor(mx, o, 32));
      float ex = __expf(e - mx);
      float den = ex;
      for (int o = 16; o > 0; o >>= 1) den += __shfl_xor(den, o, 32);
      abuf[t] = ex / den;
    }
    __syncthreads();
    if (t < 128) {
      float r = 0.f;
      #pragma unroll 8
      for (int nn = 0; nn < NPG; nn++) r += abuf[nn] * xs[nn*128 + t];
      hr[128 + t] = r;
    }
    __syncthreads();
    if (step == 2) break;
    // ---- gates for next step: j = t&511, input-half = t>>9 ----
    {
      int j = t & 511, half = t >> 9;
      const float* wp = Wfold + (size_t)(half*128)*512 + j;
      const float* iv = hr + half*128;
      float a0=0.f, a1=0.f, a2=0.f, a3=0.f;
      #pragma unroll 4
      for (int i = 0; i < 128; i += 4) {
        a0 += iv[i]   * wp[(i)  *512];
        a1 += iv[i+1] * wp[(i+1)*512];
        a2 += iv[i+2] * wp[(i+2)*512];
        a3 += iv[i+3] * wp[(i+3)*512];
      }
      pbuf[t] = a0 + a1 + a2 + a3;
    }
    __syncthreads();
    if (t < 128) {  // LSTM update (gate order i,f,g,o)
      float gi = pbuf[t]     + pbuf[512+t]     + bs_ih[t]     + bs_hh[t];
      float gf = pbuf[128+t] + pbuf[640+t]     + bs_ih[128+t] + bs_hh[128+t];
      float gg = pbuf[256+t] + pbuf[768+t]     + bs_ih[256+t] + bs_hh[256+t];
      float go = pbuf[384+t] + pbuf[896+t]     + bs_ih[384+t] + bs_hh[384+t];
      float ci = sigm(gf) * cbuf[t] + sigm(gi) * tanhf(gg);
      cbuf[t] = ci;
      hr[t] = sigm(go) * tanhf(ci);
    }
    __syncthreads();
  }
  if (t < 256) qpool[g*256 + t] = hr[t];
}

__global__ void yhat_k(const float* __restrict__ feat, const int* __restrict__ ei3,
                       const int* __restrict__ batch, const float* __restrict__ qpool,
                       float* __restrict__ yhat) {
  int idx = blockIdx.x * blockDim.x + threadIdx.x;
  if (idx >= N_E3 * 640) return;
  int e = idx / 640, j = idx - e * 640;
  int s0 = ei3[e], s1 = ei3[N_E3 + e];
  float v;
  if (j < 128)      { v = 0.5f * (feat[s0*128+j] + feat[s1*128+j]); }
  else if (j < 256) { int jj = j-128; v = feat[s0*128+jj] * feat[s1*128+jj]; }
  else if (j < 384) { int jj = j-256; float d = feat[s0*128+jj] - feat[s1*128+jj]; v = d*d; }
  else              { int cbi = batch[s0]; v = qpool[cbi*256 + (j-384)]; }
  yhat[idx] = v;
}

__global__ void final_k(const float* __restrict__ yhat,
                        const float* __restrict__ mean, const float* __restrict__ var,
                        const float* __restrict__ g, const float* __restrict__ b,
                        const float* __restrict__ ea3,
                        const float* __restrict__ Ww, const float* __restrict__ Wb,
                        float* __restrict__ out) {
  int e = blockIdx.x, t = threadIdx.x;  // 128 threads
  __shared__ float red[128];
  float av[8];
  #pragma unroll
  for (int k = 0; k < 8; k++) av[k] = ea3[e*8 + k];
  float acc = 0.f;
  for (int j = t; j < 640; j += 128) {
    float yn = (yhat[(size_t)e*640 + j] - mean[j]) * rsqrtf(var[j] + BN_EPS) * g[j] + b[j];
    float wj = 0.f;
    #pragma unroll
    for (int k = 0; k < 8; k++) wj += av[k] * Ww[k*640 + j];
    acc += yn * wj;
  }
  red[t] = acc; __syncthreads();
  for (int w = 64; w > 0; w >>= 1) {
    if (t < w) red[t] += red[t+w];
    __syncthreads();
  }
  if (t == 0) {
    float bb = 0.f;
    #pragma unroll
    for (int k = 0; k < 8; k++) bb += av[k] * Wb[k];
    out[e] = red[0] + bb;
  }
}

extern "C" void kernel_launch(void* const* d_in, const int* in_sizes, int n_in,
                              void* d_out, int out_size, void* d_ws, size_t ws_size,
                              hipStream_t stream) {
  const float* x      = (const float*)d_in[0];
  const int*   ei     = (const int*)  d_in[1];
  const float* eattr  = (const float*)d_in[2];
  const int*   ei3    = (const int*)  d_in[3];
  const float* ea3    = (const float*)d_in[4];
  const int*   batch  = (const int*)  d_in[5];
  const float* bnx_g  = (const float*)d_in[6];
  const float* bnx_b  = (const float*)d_in[7];
  const float* Wn     = (const float*)d_in[8];
  const float* bnode  = (const float*)d_in[9];
  const float* We     = (const float*)d_in[10];
  const float* be     = (const float*)d_in[11];
  const float* Wnn1   = (const float*)d_in[12];
  const float* bias1  = (const float*)d_in[13];
  const float* Wih1   = (const float*)d_in[14];
  const float* Whh1   = (const float*)d_in[15];
  const float* bih1   = (const float*)d_in[16];
  const float* bhh1   = (const float*)d_in[17];
  const float* bnc_g  = (const float*)d_in[18];
  const float* bnc_b  = (const float*)d_in[19];
  const float* Wc1    = (const float*)d_in[20];
  const float* bc1    = (const float*)d_in[21];
  const float* Wc2    = (const float*)d_in[22];
  const float* bc2    = (const float*)d_in[23];
  const float* Wnn2   = (const float*)d_in[24];
  const float* bias2  = (const float*)d_in[25];
  const float* Wih2   = (const float*)d_in[26];
  const float* Whh2   = (const float*)d_in[27];
  const float* bih2   = (const float*)d_in[28];
  const float* bhh2   = (const float*)d_in[29];
  const float* Ws_ih  = (const float*)d_in[30];
  const float* Ws_hh  = (const float*)d_in[31];
  const float* bs_ih  = (const float*)d_in[32];
  const float* bs_hh  = (const float*)d_in[33];
  const float* bno_g  = (const float*)d_in[34];
  const float* bno_b  = (const float*)d_in[35];
  const float* Ww     = (const float*)d_in[36];
  const float* Wb     = (const float*)d_in[37];
  float* out = (float*)d_out;

  // workspace carve-up (floats)
  float* W = (float*)d_ws;
  size_t off = 0;
  float* Wz1   = W + off; off += 49152;                  // [768][64]
  float* Wfold = W + off; off += 131072;                 // [256][512]
  float* W2f   = W + off; off += 131072;                 // [128][1024]
  float* ea12  = W + off; off += (size_t)N_EDGES * 12;
  float* nodeA = W + off; off += (size_t)N_NODES * 64;
  float* sbuf  = W + off; off += (size_t)N_NODES * 128;
  float* cnt1  = W + off; off += (size_t)N_NODES;
  float* cnt2  = W + off; off += (size_t)N_NODES;
  float* y1    = W + off; off += (size_t)N_NODES * 128;
  float* nodeB = W + off; off += (size_t)N_NODES * 128;
  float* Z     = W + off; off += (size_t)N_NODES * 768;  // aliased: gates / Zg
  float* qpool = W + off; off += (size_t)NGRAPH * 256;
  float* yhat  = W + off; off += (size_t)N_E3 * 640;
  float* mean  = W + off; off += 640;
  float* var   = W + off; off += 640;
  (void)off; (void)ws_size; (void)in_sizes; (void)n_in; (void)out_size;

  float* gatesI1 = Z;                          // [8192,192]
  float* gatesH1 = Z + (size_t)N_NODES * 192;
  float* gatesI2 = Z;                          // [8192,384]
  float* gatesH2 = Z + (size_t)N_NODES * 384;
  float* Zg      = Z;                          // [2048,1024]

  // 0. one-time packs (also zeros cnt) + counts
  pack_k<<<512, 256, 0, stream>>>(Wnn1, Ws_ih, Ws_hh, Wnn2, Wz1, Wfold, W2f, cnt1, cnt2);
  cnt_k<<<(N_EDGES+255)/256, 256, 0, stream>>>(ei, ei3, cnt1, cnt2);

  // 1. embeds
  bn_stats_k<<<8, 256, 0, stream>>>(x, N_NODES, 8, mean, var);
  embed_k<<<2048 + 768, 256, 0, stream>>>(x, mean, var, bnx_g, bnx_b, Wn, bnode, nodeA,
                                          eattr, We, be, ea12);

  // 2. layer-1 x2: Z GEMM (+zero sbuf) -> scatter -> dual gate GEMM -> combine
  for (int it = 0; it < 2; it++) {
    gemm_k<true,0,0><<<1536 + 16, 256, 0, stream>>>(nodeA, Wz1, nullptr,
        nullptr, nullptr, nullptr, nullptr, nullptr, Z, N_NODES, 64, 768,
        1536, sbuf, N_NODES*64);
    conv1_msg_k<<<(N_EDGES*64)/256, 256, 0, stream>>>(Z, ei, ea12, sbuf);
    gemm2_k<true,1,true,0><<<768, 256, 0, stream>>>(
        sbuf,  Wih1, bih1, cnt1, bias1, gatesI1, N_NODES, 64, 192, 384,
        nodeA, Whh1, bhh1,               gatesH1, N_NODES, 64, 192);
    gru_combine_k<6><<<(N_NODES*64)/256, 256, 0, stream>>>(gatesI1, gatesH1, nodeA);
  }

  // 3. BN (fused into fc1) + FC1 + FC2
  bn_stats_k<<<64, 256, 0, stream>>>(nodeA, N_NODES, 64, mean, var);
  gemm_k<false,1,2><<<(N_NODES/64)*(128/64), 256, 0, stream>>>(nodeA, Wc1, bc1,
      mean, var, bnc_g, bnc_b, nullptr, y1, N_NODES, 64, 128,
      (N_NODES/64)*(128/64), nullptr, 0);
  gemm_k<false,1,0><<<(N_NODES/64)*(128/64), 256, 0, stream>>>(y1, Wc2, bc2,
      nullptr, nullptr, nullptr, nullptr, nullptr, nodeB, N_NODES, 128, 128,
      (N_NODES/64)*(128/64), nullptr, 0);

  // 4. layer-2 x2: Zg GEMM (row-gather via ei3, +zero sbuf) -> scatter -> dual gate GEMM -> combine
  for (int it = 0; it < 2; it++) {
    gemm_k<false,0,0><<<512 + 16, 256, 0, stream>>>(nodeB, W2f, nullptr,
        nullptr, nullptr, nullptr, nullptr, ei3, Zg, 2*N_E3, 128, 1024,
        512, sbuf, N_NODES*128);
    conv2_msg_k<<<(2*N_E3*128)/256, 256, 0, stream>>>(Zg, ei3, ea3, sbuf);
    gemm2_k<true,1,true,0><<<1536, 256, 0, stream>>>(
        sbuf,  Wih2, bih2, cnt2, bias2, gatesI2, N_NODES, 128, 384, 768,
        nodeB, Whh2, bhh2,               gatesH2, N_NODES, 128, 384);
    gru_combine_k<7><<<(N_NODES*128)/256, 256, 0, stream>>>(gatesI2, gatesH2, nodeB);
  }

  // 5. set2set
  set2set_k<<<NGRAPH, 1024, 0, stream>>>(nodeB, Wfold, bs_ih, bs_hh, qpool);

  // 6. yhat + BN + weighted sum
  yhat_k<<<(N_E3*640 + 255)/256, 256, 0, stream>>>(nodeB, ei3, batch, qpool, yhat);
  bn_stats_k<<<640, 256, 0, stream>>>(yhat, N_E3, 640, mean, var);
  final_k<<<N_E3, 128, 0, stream>>>(yhat, mean, var, bno_g, bno_b, ea3, Ww, Wb, out);
}